// Round 14
// baseline (638.466 us; speedup 1.0000x reference)
//
#include <hip/hip_runtime.h>
#include <hip/hip_bf16.h>

#define N_NODES 16384
#define E_EDGES 262144
#define IN_DIM 512

// fixed-point scale for deterministic aggregation
#define AGG_SCALE 1099511627776.0   // 2^40
#define AGG_INV   (1.0/1099511627776.0)

typedef __attribute__((ext_vector_type(8))) short bf16x8;
typedef __attribute__((ext_vector_type(4))) float f32x4;

// ---------------- edge dtype detection + access ----------------
__global__ void detect_kernel(const void* __restrict__ ei, unsigned* __restrict__ diag) {
    const unsigned long long v = ((const unsigned long long*)ei)[threadIdx.x];
    const int small = (v < 16384ull) ? 1 : 0;
    const int all64 = __all(small);
    if (threadIdx.x == 0) diag[0] = all64 ? 1u : 0u;
}

__device__ __forceinline__ int edge_at(const void* __restrict__ ei, int is64, int pos) {
    return is64 ? (int)(((const long long*)ei)[pos]) : ((const int*)ei)[pos];
}

// ---------------- degree ----------------
__global__ __launch_bounds__(256) void deg_kernel(const void* __restrict__ ei,
                                                  const unsigned* __restrict__ diag,
                                                  int* __restrict__ deg) {
    const int is64 = (int)diag[0];
    int e = blockIdx.x * 256 + threadIdx.x;
    int r = edge_at(ei, is64, e);
    if (r >= 0 && r < N_NODES) atomicAdd(&deg[r], 1);
}

// ---------------- exclusive prefix scan of deg -> offs; also dinv (fused) ----------------
__global__ __launch_bounds__(256) void scan_kernel(const int* __restrict__ deg, int* __restrict__ offs,
                                                   float* __restrict__ dinv) {
    __shared__ int part[257];
    const int t = threadIdx.x;
    const int base = t * 64;
    int s = 0;
    #pragma unroll 4
    for (int i = 0; i < 64; ++i) s += deg[base + i];
    part[t + 1] = s;
    if (t == 0) part[0] = 0;
    __syncthreads();
    if (t == 0) {
        int acc = 0;
        for (int i = 1; i <= 256; ++i) { acc += part[i]; part[i] = acc; }
    }
    __syncthreads();
    int run = part[t];                      // exclusive offset of chunk t
    for (int i = 0; i < 64; ++i) {
        const int d = deg[base + i];
        offs[base + i] = run; run += d;
        dinv[base + i] = (d > 0) ? __fdiv_rn(1.0f, __fsqrt_rn((float)d)) : 0.0f;
    }
    if (t == 255) offs[N_NODES] = run;
}

// ---------------- scatter edges into CSR slots ----------------
__global__ __launch_bounds__(256) void scatter_kernel(
    const void* __restrict__ ei, const unsigned* __restrict__ diag,
    const int* __restrict__ offs, int* __restrict__ cursor, int* __restrict__ ecol_s)
{
    const int is64 = (int)diag[0];
    int e = blockIdx.x * 256 + threadIdx.x;
    int r  = edge_at(ei, is64, e);
    if (r < 0 || r >= N_NODES) return;
    int cc = edge_at(ei, is64, E_EDGES + e);
    int pos = atomicAdd(&cursor[r], 1);
    ecol_s[offs[r] + pos] = (cc >= 0 && cc < N_NODES) ? cc : -1;
}

// ---------------- MLP: f32, k-ascending single-accumulator fmaf chains ----------------
__device__ __forceinline__ void dense_layer32(float (*hsw)[64], int c,
                                              const float* __restrict__ WP,
                                              const float* __restrict__ BP,
                                              bool relu, bool last,
                                              float* __restrict__ gout, int n0)
{
    float s0 = 0.0f, s1 = 0.0f, s2 = 0.0f, s3 = 0.0f;
    #pragma unroll 4
    for (int k = 0; k < 64; ++k) {
        const float wv = WP[k * 64 + c];
        s0 = fmaf(hsw[0][k], wv, s0);
        s1 = fmaf(hsw[1][k], wv, s1);
        s2 = fmaf(hsw[2][k], wv, s2);
        s3 = fmaf(hsw[3][k], wv, s3);
    }
    const float bv = BP[c];
    s0 += bv; s1 += bv; s2 += bv; s3 += bv;
    if (relu) { s0 = fmaxf(s0, 0.0f); s1 = fmaxf(s1, 0.0f); s2 = fmaxf(s2, 0.0f); s3 = fmaxf(s3, 0.0f); }
    __syncthreads();
    if (last) {
        gout[(size_t)(n0 + 0) * 64 + c] = s0;
        gout[(size_t)(n0 + 1) * 64 + c] = s1;
        gout[(size_t)(n0 + 2) * 64 + c] = s2;
        gout[(size_t)(n0 + 3) * 64 + c] = s3;
    } else {
        hsw[0][c] = s0; hsw[1][c] = s1; hsw[2][c] = s2; hsw[3][c] = s3;
    }
    __syncthreads();
}

__global__ __launch_bounds__(256) void mlp_kernel(
    const float* __restrict__ x,
    const float* __restrict__ W1, const float* __restrict__ b1,
    const float* __restrict__ W2, const float* __restrict__ b2,
    const float* __restrict__ W3, const float* __restrict__ b3,
    const float* __restrict__ W4, const float* __restrict__ b4,
    const float* __restrict__ Wg1, const float* __restrict__ bg1,
    const float* __restrict__ Wg2, const float* __restrict__ bg2,
    float* __restrict__ g32)
{
    __shared__ float hs[4][4][64];
    const int w = threadIdx.x >> 6;
    const int c = threadIdx.x & 63;
    const int n0 = blockIdx.x * 16 + w * 4;

    float a0 = 0.0f, a1 = 0.0f, a2 = 0.0f, a3 = 0.0f;
    const float* xp = x + (size_t)n0 * IN_DIM;
    #pragma unroll 4
    for (int k = 0; k < IN_DIM; ++k) {
        const float wv = W1[k * 64 + c];
        a0 = fmaf(xp[k],              wv, a0);
        a1 = fmaf(xp[IN_DIM + k],     wv, a1);
        a2 = fmaf(xp[2 * IN_DIM + k], wv, a2);
        a3 = fmaf(xp[3 * IN_DIM + k], wv, a3);
    }
    const float bv = b1[c];
    hs[w][0][c] = fmaxf(a0 + bv, 0.0f);
    hs[w][1][c] = fmaxf(a1 + bv, 0.0f);
    hs[w][2][c] = fmaxf(a2 + bv, 0.0f);
    hs[w][3][c] = fmaxf(a3 + bv, 0.0f);
    __syncthreads();

    dense_layer32(hs[w], c, W2, b2, false, false, g32, n0);
    dense_layer32(hs[w], c, W3, b3, true,  false, g32, n0);
    dense_layer32(hs[w], c, W4, b4, false, false, g32, n0);
    dense_layer32(hs[w], c, Wg1, bg1, true, false, g32, n0);
    dense_layer32(hs[w], c, Wg2, bg2, false, true, g32, n0);
}

// ---------------- CSR aggregation + finalize (fused): one wave per row ----------------
__global__ __launch_bounds__(256) void aggcsr_kernel(
    const int* __restrict__ offs, const int* __restrict__ ecol_s,
    const float* __restrict__ dinv, const float* __restrict__ g32,
    float* __restrict__ F32, short* __restrict__ Fb)
{
    const int r = (blockIdx.x << 2) + (threadIdx.x >> 6);
    const int h = threadIdx.x & 63;
    const float dr = dinv[r];
    const int b = offs[r], e2 = offs[r + 1];
    long long sum = 0;
    #pragma unroll 1
    for (int i = b; i < e2; ++i) {
        const int cc = ecol_s[i];
        if (cc < 0) continue;
        const float m = __fmul_rn(__fmul_rn(dr, dinv[cc]), g32[((size_t)cc << 6) + h]);
        sum += __double2ll_rn((double)m * AGG_SCALE);
    }
    const float a = (float)((double)sum * AGG_INV);
    const int idx = (r << 6) + h;
    const float f = g32[idx] - a;
    F32[idx] = f;
    __hip_bfloat16 hb = __float2bfloat16(f);
    Fb[idx] = *(short*)&hb;
}

// ---------------- MFMA bf16 screening: ct-split waves + LDS top-6 merge ----------------
// med3-form sorted insert: depth-2, 11 ops (min(a,max(b,x)) fuses to v_med3_u32).
// Keys/candidates bit-identical to the 12-op bubble version.
__device__ __forceinline__ void ins6(unsigned* k, unsigned x) {
    const unsigned r0 = max(k[0], x);
    k[5] = min(k[4], max(k[5], x));
    k[4] = min(k[3], max(k[4], x));
    k[3] = min(k[2], max(k[3], x));
    k[2] = min(k[1], max(k[2], x));
    k[1] = min(k[0], max(k[1], x));
    k[0] = r0;
}

__global__ __launch_bounds__(256) void screen_kernel(
    const short* __restrict__ Fb, int* __restrict__ cand)
{
    __shared__ unsigned mk[4][64][25];   // 25600 B (pad 24->25: conflict-free)
    const int l = threadIdx.x & 63;
    const int w = threadIdx.x >> 6;
    const int rb = blockIdx.x >> 1;
    const int sp = blockIdx.x & 1;
    const int r0 = rb * 16;
    const int c0 = sp * 8192 + w * 2048;   // this wave's quarter

    // A fragments: lane l <- Fb[r0 + (l&15)][8*(l>>4) .. +7] and +32
    const short* ap = Fb + ((size_t)(r0 + (l & 15)) << 6) + ((l >> 4) << 3);
    const bf16x8 a0 = *(const bf16x8*)(ap);
    const bf16x8 a1 = *(const bf16x8*)(ap + 32);

    unsigned keys[4][6];
    #pragma unroll
    for (int r = 0; r < 4; ++r)
        #pragma unroll
        for (int t = 0; t < 6; ++t) keys[r][t] = 0u;

    const short* bp0 = Fb + ((size_t)(c0 + (l & 15)) << 6) + ((l >> 4) << 3);
    const int invbase = 16383 - c0 - (l & 15);

    bf16x8 p0b0 = *(const bf16x8*)(bp0);
    bf16x8 p0b1 = *(const bf16x8*)(bp0 + 32);
    bf16x8 p1b0 = *(const bf16x8*)(bp0 + 1024);
    bf16x8 p1b1 = *(const bf16x8*)(bp0 + 1024 + 32);

    #pragma unroll 4
    for (int ct = 0; ct < 128; ++ct) {
        const bf16x8 b0 = p0b0;
        const bf16x8 b1 = p0b1;
        p0b0 = p1b0; p0b1 = p1b1;
        if (ct + 2 < 128) {
            const short* bp = bp0 + ((ct + 2) << 10);
            p1b0 = *(const bf16x8*)(bp);
            p1b1 = *(const bf16x8*)(bp + 32);
        }
        f32x4 acc = {0.0f, 0.0f, 0.0f, 0.0f};
        acc = __builtin_amdgcn_mfma_f32_16x16x32_bf16(a0, b0, acc, 0, 0, 0);
        acc = __builtin_amdgcn_mfma_f32_16x16x32_bf16(a1, b1, acc, 0, 0, 0);
        const unsigned invcol = (unsigned)(invbase - (ct << 4));
        #pragma unroll
        for (int r = 0; r < 4; ++r) {
            const unsigned bits = __float_as_uint(acc[r]);
            const unsigned mask = (unsigned)((int)bits >> 31) | 0x80000000u;
            const unsigned key = ((bits ^ mask) & 0xFFFFC000u) | invcol;
            ins6(keys[r], key);
        }
    }

    // publish this wave's lists
    #pragma unroll
    for (int r = 0; r < 4; ++r)
        #pragma unroll
        for (int t = 0; t < 6; ++t)
            mk[w][l][r * 6 + t] = keys[r][t];
    __syncthreads();

    // merge: thread (row=tid>>4, cls=tid&15) merges 4 waves' top-6 for its (row,class)
    const int tid = threadIdx.x;
    const int row = tid >> 4;
    const int cls = tid & 15;
    const int srcl = ((row >> 2) << 4) + cls;   // source lane holding (row,cls)
    const int rbase = (row & 3) * 6;            // reg index within that lane
    unsigned m[6];
    #pragma unroll
    for (int t = 0; t < 6; ++t) m[t] = mk[0][srcl][rbase + t];
    #pragma unroll
    for (int w2 = 1; w2 < 4; ++w2)
        #pragma unroll
        for (int t = 0; t < 6; ++t) ins6(m, mk[w2][srcl][rbase + t]);

    const int grow = r0 + row;
    int* cp = cand + ((size_t)(sp * N_NODES + grow)) * 96 + cls * 6;
    #pragma unroll
    for (int t = 0; t < 6; ++t) cp[t] = 16383 - (int)(m[t] & 0x3FFFu);
}

// ---------------- refine2: LDS-staged exact f32-chain recompute of 192 cands -> stable top-8 ----------------
__global__ __launch_bounds__(256) void refine2_kernel(
    const float* __restrict__ F, const int* __restrict__ cand,
    float* __restrict__ resv, int* __restrict__ residx)
{
    __shared__ float sfr[64];
    __shared__ float scand[192 * 65];   // 49920 B
    __shared__ float sval[256];
    __shared__ int   sidx[256];
    const int t = threadIdx.x;
    const int row = blockIdx.x;

    if (t < 64) sfr[t] = F[(size_t)row * 64 + t];

    // stage 192 candidate rows: slot s = i*16 + (t>>4), 16 threads x float4 = 256B per row
    const int g = t >> 4, qq = t & 15;
    #pragma unroll 1
    for (int i = 0; i < 12; ++i) {
        const int s = i * 16 + g;
        const int sp = (s >= 96) ? 1 : 0;
        const int slot = s - 96 * sp;
        const int cidx = cand[((size_t)(sp * N_NODES + row)) * 96 + slot];
        const float4 v = *(const float4*)(F + ((size_t)cidx << 6) + (qq << 2));
        float* d = &scand[s * 65 + (qq << 2)];
        d[0] = v.x; d[1] = v.y; d[2] = v.z; d[3] = v.w;
    }
    __syncthreads();

    float s = -3.0e38f;
    int c = 1 << 30;
    if (t < 192) {
        const int sp = (t >= 96) ? 1 : 0;
        const int slot = t - 96 * sp;
        c = cand[((size_t)(sp * N_NODES + row)) * 96 + slot];
        const float* fp = &scand[t * 65];
        float acc = 0.0f;
        #pragma unroll 8
        for (int k = 0; k < 64; ++k) acc = fmaf(sfr[k], fp[k], acc);  // k-ascending exact chain
        s = acc;
    }
    sval[t] = s; sidx[t] = c;
    __syncthreads();

    if (t < 64) {
        float v0 = sval[t], v1 = sval[t + 64], v2 = sval[t + 128];
        int   i0 = sidx[t], i1 = sidx[t + 64], i2 = sidx[t + 128];
        #pragma unroll 1
        for (int it = 0; it < 8; ++it) {
            float bv = v0; int bi = i0;
            if (v1 > bv || (v1 == bv && i1 < bi)) { bv = v1; bi = i1; }
            if (v2 > bv || (v2 == bv && i2 < bi)) { bv = v2; bi = i2; }
            #pragma unroll
            for (int off = 32; off > 0; off >>= 1) {
                float ov = __shfl_xor(bv, off);
                int   oi = __shfl_xor(bi, off);
                if (ov > bv || (ov == bv && oi < bi)) { bv = ov; bi = oi; }
            }
            if (t == 0) {
                resv[(size_t)row * 8 + it] = bv;
                residx[(size_t)row * 8 + it] = bi;
            }
            if (i0 == bi) v0 = -3.4e38f;   // cols distinct per row
            if (i1 == bi) v1 = -3.4e38f;
            if (i2 == bi) v2 = -3.4e38f;
        }
    }
}

// ---------------- emit: FLOAT32 outputs ----------------
__global__ __launch_bounds__(256) void emit_kernel(
    const float* __restrict__ resv, const int* __restrict__ residx,
    float* __restrict__ out)
{
    const int j = blockIdx.x * 256 + threadIdx.x;
    if (j < 131072) {
        out[j] = resv[j];                             // topk_vals
    } else if (j < 262144) {
        out[j] = (float)((j - 131072) >> 3);          // new_edge_index row 0: src = slot/8
    } else {
        out[j] = (float)residx[j - 262144];           // new_edge_index row 1: topk_idx
    }
}

__global__ void canary_kernel(float* out, float code) {
    out[0] = code;
}

// ---------------- launch ----------------
extern "C" void kernel_launch(void* const* d_in, const int* in_sizes, int n_in,
                              void* d_out, int out_size, void* d_ws, size_t ws_size,
                              hipStream_t stream)
{
    const float* x   = (const float*)d_in[0];
    const void*  ei  = d_in[1];
    const float* W1  = (const float*)d_in[2];  const float* b1  = (const float*)d_in[3];
    const float* W2  = (const float*)d_in[4];  const float* b2  = (const float*)d_in[5];
    const float* W3  = (const float*)d_in[6];  const float* b3  = (const float*)d_in[7];
    const float* W4  = (const float*)d_in[8];  const float* b4  = (const float*)d_in[9];
    const float* Wg1 = (const float*)d_in[10]; const float* bg1 = (const float*)d_in[11];
    const float* Wg2 = (const float*)d_in[12]; const float* bg2 = (const float*)d_in[13];
    float* out = (float*)d_out;

    // workspace layout (stream-ordered overlays):
    //   g32   [0, 4M)
    //   F32   [4M, 8M)
    //   Fb    [8M, 10M)
    //   cand  [10M, 22M)  -- first 1.2M overlaid by CSR scratch (dead before screen):
    //       ecol_s [10M, 11M), cursor [11M, +64K), offs [11M+64K, +68K)
    //   resv  [22M, 22.5M) residx [22.5M, 23M)
    //   deg [23M, +64K) dinv [+64K, +128K) diag [+128K]
    char* ws = (char*)d_ws;
    float* g32 = (float*)(ws);
    float* F32 = (float*)(ws + ((size_t)4 << 20));
    short* Fb  = (short*)(ws + ((size_t)8 << 20));
    int*   cand   = (int*)(ws + ((size_t)10 << 20));
    int*   ecol_s = (int*)(ws + ((size_t)10 << 20));
    int*   cursor = (int*)(ws + ((size_t)11 << 20));
    int*   offs   = (int*)(ws + ((size_t)11 << 20) + (1u << 16));
    float* resv = (float*)(ws + ((size_t)22 << 20));
    int*   residx = (int*)(ws + ((size_t)22 << 20) + ((size_t)1 << 19));
    int*   deg   = (int*)(ws + ((size_t)23 << 20));
    float* dinvf = (float*)(ws + ((size_t)23 << 20) + (1u << 16));
    unsigned* diag = (unsigned*)(ws + ((size_t)23 << 20) + (2u << 16));

    const size_t NEEDED = ((size_t)23 << 20) + (2u << 16) + 256;
    if (ws_size < NEEDED || n_in < 14) {
        canary_kernel<<<1, 1, 0, stream>>>(out, ws_size < NEEDED ? 5000.0f : 3000.0f);
        return;
    }

    hipMemsetAsync(deg, 0, N_NODES * sizeof(int), stream);
    hipMemsetAsync(cursor, 0, N_NODES * sizeof(int), stream);

    detect_kernel<<<1, 64, 0, stream>>>(ei, diag);
    deg_kernel<<<E_EDGES / 256, 256, 0, stream>>>(ei, diag, deg);
    scan_kernel<<<1, 256, 0, stream>>>(deg, offs, dinvf);
    scatter_kernel<<<E_EDGES / 256, 256, 0, stream>>>(ei, diag, offs, cursor, ecol_s);
    mlp_kernel<<<N_NODES / 16, 256, 0, stream>>>(x, W1, b1, W2, b2, W3, b3, W4, b4, Wg1, bg1, Wg2, bg2, g32);
    aggcsr_kernel<<<N_NODES / 4, 256, 0, stream>>>(offs, ecol_s, dinvf, g32, F32, Fb);
    screen_kernel<<<2048, 256, 0, stream>>>(Fb, cand);
    refine2_kernel<<<N_NODES, 256, 0, stream>>>(F32, cand, resv, residx);
    emit_kernel<<<(N_NODES * 24) / 256, 256, 0, stream>>>(resv, residx, out);
}

// Round 15
// 559.647 us; speedup vs baseline: 1.1408x; 1.1408x over previous
//
#include <hip/hip_runtime.h>
#include <hip/hip_bf16.h>

#define N_NODES 16384
#define E_EDGES 262144
#define IN_DIM 512

// fixed-point scale for deterministic aggregation
#define AGG_SCALE 1099511627776.0   // 2^40
#define AGG_INV   (1.0/1099511627776.0)

typedef __attribute__((ext_vector_type(8))) short bf16x8;
typedef __attribute__((ext_vector_type(4))) float f32x4;

// ---------------- edge dtype detection + access ----------------
__global__ void detect_kernel(const void* __restrict__ ei, unsigned* __restrict__ diag) {
    const unsigned long long v = ((const unsigned long long*)ei)[threadIdx.x];
    const int small = (v < 16384ull) ? 1 : 0;
    const int all64 = __all(small);
    if (threadIdx.x == 0) diag[0] = all64 ? 1u : 0u;
}

__device__ __forceinline__ int edge_at(const void* __restrict__ ei, int is64, int pos) {
    return is64 ? (int)(((const long long*)ei)[pos]) : ((const int*)ei)[pos];
}

// ---------------- degree ----------------
__global__ __launch_bounds__(256) void deg_kernel(const void* __restrict__ ei,
                                                  const unsigned* __restrict__ diag,
                                                  int* __restrict__ deg) {
    const int is64 = (int)diag[0];
    int e = blockIdx.x * 256 + threadIdx.x;
    int r = edge_at(ei, is64, e);
    if (r >= 0 && r < N_NODES) atomicAdd(&deg[r], 1);
}

// ---------------- exclusive prefix scan of deg -> offs; also dinv (fused) ----------------
__global__ __launch_bounds__(256) void scan_kernel(const int* __restrict__ deg, int* __restrict__ offs,
                                                   float* __restrict__ dinv) {
    __shared__ int part[257];
    const int t = threadIdx.x;
    const int base = t * 64;
    int s = 0;
    #pragma unroll 4
    for (int i = 0; i < 64; ++i) s += deg[base + i];
    part[t + 1] = s;
    if (t == 0) part[0] = 0;
    __syncthreads();
    if (t == 0) {
        int acc = 0;
        for (int i = 1; i <= 256; ++i) { acc += part[i]; part[i] = acc; }
    }
    __syncthreads();
    int run = part[t];                      // exclusive offset of chunk t
    for (int i = 0; i < 64; ++i) {
        const int d = deg[base + i];
        offs[base + i] = run; run += d;
        dinv[base + i] = (d > 0) ? __fdiv_rn(1.0f, __fsqrt_rn((float)d)) : 0.0f;
    }
    if (t == 255) offs[N_NODES] = run;
}

// ---------------- scatter edges into CSR slots ----------------
__global__ __launch_bounds__(256) void scatter_kernel(
    const void* __restrict__ ei, const unsigned* __restrict__ diag,
    const int* __restrict__ offs, int* __restrict__ cursor, int* __restrict__ ecol_s)
{
    const int is64 = (int)diag[0];
    int e = blockIdx.x * 256 + threadIdx.x;
    int r  = edge_at(ei, is64, e);
    if (r < 0 || r >= N_NODES) return;
    int cc = edge_at(ei, is64, E_EDGES + e);
    int pos = atomicAdd(&cursor[r], 1);
    ecol_s[offs[r] + pos] = (cc >= 0 && cc < N_NODES) ? cc : -1;
}

// ---------------- MLP: f32, k-ascending single-accumulator fmaf chains ----------------
__device__ __forceinline__ void dense_layer32(float (*hsw)[64], int c,
                                              const float* __restrict__ WP,
                                              const float* __restrict__ BP,
                                              bool relu, bool last,
                                              float* __restrict__ gout, int n0)
{
    float s0 = 0.0f, s1 = 0.0f, s2 = 0.0f, s3 = 0.0f;
    #pragma unroll 4
    for (int k = 0; k < 64; ++k) {
        const float wv = WP[k * 64 + c];
        s0 = fmaf(hsw[0][k], wv, s0);
        s1 = fmaf(hsw[1][k], wv, s1);
        s2 = fmaf(hsw[2][k], wv, s2);
        s3 = fmaf(hsw[3][k], wv, s3);
    }
    const float bv = BP[c];
    s0 += bv; s1 += bv; s2 += bv; s3 += bv;
    if (relu) { s0 = fmaxf(s0, 0.0f); s1 = fmaxf(s1, 0.0f); s2 = fmaxf(s2, 0.0f); s3 = fmaxf(s3, 0.0f); }
    __syncthreads();
    if (last) {
        gout[(size_t)(n0 + 0) * 64 + c] = s0;
        gout[(size_t)(n0 + 1) * 64 + c] = s1;
        gout[(size_t)(n0 + 2) * 64 + c] = s2;
        gout[(size_t)(n0 + 3) * 64 + c] = s3;
    } else {
        hsw[0][c] = s0; hsw[1][c] = s1; hsw[2][c] = s2; hsw[3][c] = s3;
    }
    __syncthreads();
}

__global__ __launch_bounds__(256) void mlp_kernel(
    const float* __restrict__ x,
    const float* __restrict__ W1, const float* __restrict__ b1,
    const float* __restrict__ W2, const float* __restrict__ b2,
    const float* __restrict__ W3, const float* __restrict__ b3,
    const float* __restrict__ W4, const float* __restrict__ b4,
    const float* __restrict__ Wg1, const float* __restrict__ bg1,
    const float* __restrict__ Wg2, const float* __restrict__ bg2,
    float* __restrict__ g32)
{
    __shared__ float hs[4][4][64];
    const int w = threadIdx.x >> 6;
    const int c = threadIdx.x & 63;
    const int n0 = blockIdx.x * 16 + w * 4;

    float a0 = 0.0f, a1 = 0.0f, a2 = 0.0f, a3 = 0.0f;
    const float* xp = x + (size_t)n0 * IN_DIM;
    #pragma unroll 4
    for (int k = 0; k < IN_DIM; ++k) {
        const float wv = W1[k * 64 + c];
        a0 = fmaf(xp[k],              wv, a0);
        a1 = fmaf(xp[IN_DIM + k],     wv, a1);
        a2 = fmaf(xp[2 * IN_DIM + k], wv, a2);
        a3 = fmaf(xp[3 * IN_DIM + k], wv, a3);
    }
    const float bv = b1[c];
    hs[w][0][c] = fmaxf(a0 + bv, 0.0f);
    hs[w][1][c] = fmaxf(a1 + bv, 0.0f);
    hs[w][2][c] = fmaxf(a2 + bv, 0.0f);
    hs[w][3][c] = fmaxf(a3 + bv, 0.0f);
    __syncthreads();

    dense_layer32(hs[w], c, W2, b2, false, false, g32, n0);
    dense_layer32(hs[w], c, W3, b3, true,  false, g32, n0);
    dense_layer32(hs[w], c, W4, b4, false, false, g32, n0);
    dense_layer32(hs[w], c, Wg1, bg1, true, false, g32, n0);
    dense_layer32(hs[w], c, Wg2, bg2, false, true, g32, n0);
}

// ---------------- CSR aggregation + finalize (fused): one wave per row ----------------
__global__ __launch_bounds__(256) void aggcsr_kernel(
    const int* __restrict__ offs, const int* __restrict__ ecol_s,
    const float* __restrict__ dinv, const float* __restrict__ g32,
    float* __restrict__ F32, short* __restrict__ Fb)
{
    const int r = (blockIdx.x << 2) + (threadIdx.x >> 6);
    const int h = threadIdx.x & 63;
    const float dr = dinv[r];
    const int b = offs[r], e2 = offs[r + 1];
    long long sum = 0;
    #pragma unroll 1
    for (int i = b; i < e2; ++i) {
        const int cc = ecol_s[i];
        if (cc < 0) continue;
        const float m = __fmul_rn(__fmul_rn(dr, dinv[cc]), g32[((size_t)cc << 6) + h]);
        sum += __double2ll_rn((double)m * AGG_SCALE);
    }
    const float a = (float)((double)sum * AGG_INV);
    const int idx = (r << 6) + h;
    const float f = g32[idx] - a;
    F32[idx] = f;
    __hip_bfloat16 hb = __float2bfloat16(f);
    Fb[idx] = *(short*)&hb;
}

// ---------------- MFMA bf16 screening: LDS-staged B panel shared by 4 waves ----------------
// grid = 512: 256 row-blocks of 64 x 2 col-splits of 8192. Block = 4 waves; wave w owns
// rows [r0+16w, +16) and scans the FULL split; B staged per 128-col tile in LDS
// (double-buffered, granule-XOR swizzle), shared by all 4 waves -> 4x less L1 traffic.
// Candidates bit-identical to prior rounds (per-class top-6 over 512-col classes).
// Key: (order-preserving float bits & 0xFFFFC000) | (16383 - col).
// C layout (verified m89/m91): col = lane&15, row = (lane>>4)*4 + reg.
__device__ __forceinline__ void ins6(unsigned* k, unsigned x) {
    const unsigned r0 = max(k[0], x);
    k[5] = min(k[4], max(k[5], x));
    k[4] = min(k[3], max(k[4], x));
    k[3] = min(k[2], max(k[3], x));
    k[2] = min(k[1], max(k[2], x));
    k[1] = min(k[0], max(k[1], x));
    k[0] = r0;
}

__global__ __launch_bounds__(256) void screen_kernel(
    const short* __restrict__ Fb, int* __restrict__ cand)
{
    __shared__ short Bt[2][128 * 64];   // 2 x 16 KB: [buf][col*64 + swizzled k]
    const int l = threadIdx.x & 63;
    const int w = threadIdx.x >> 6;
    const int rb = blockIdx.x >> 1;
    const int sp = blockIdx.x & 1;
    const int r0 = rb * 64 + w * 16;
    const int c0 = sp * 8192;

    // A fragments: lane l <- Fb[r0 + (l&15)][8*(l>>4) .. +7] and +32
    const short* ap = Fb + ((size_t)(r0 + (l & 15)) << 6) + ((l >> 4) << 3);
    const bf16x8 a0 = *(const bf16x8*)(ap);
    const bf16x8 a1 = *(const bf16x8*)(ap + 32);

    unsigned keys[4][6];
    #pragma unroll
    for (int r = 0; r < 4; ++r)
        #pragma unroll
        for (int t = 0; t < 6; ++t) keys[r][t] = 0u;

    // staging role: col = tid&127, granules jb..jb+3 (64B of the 128B row)
    const int scol = threadIdx.x & 127;
    const int jb = (threadIdx.x >> 7) * 4;
    const short* gsrc0 = Fb + ((size_t)(c0 + scol) << 6) + jb * 8;

    // prologue: stage tile 0
    bf16x8 st[4];
    #pragma unroll
    for (int j = 0; j < 4; ++j) st[j] = *(const bf16x8*)(gsrc0 + j * 8);
    #pragma unroll
    for (int j = 0; j < 4; ++j)
        *(bf16x8*)(&Bt[0][scol * 64 + (((jb + j) ^ (scol & 7)) << 3)]) = st[j];
    __syncthreads();

    const int invbase = 16383 - c0 - (l & 15);
    const int g0 = (l >> 4) ^ (l & 7);
    const int g1 = ((l >> 4) + 4) ^ (l & 7);
    int cur = 0;

    #pragma unroll 1
    for (int t = 0; t < 64; ++t) {
        // issue next tile's global loads early (latency hides under compute)
        if (t + 1 < 64) {
            const short* gs = gsrc0 + ((size_t)(t + 1) << 13);   // +128 cols * 64 shorts
            #pragma unroll
            for (int j = 0; j < 4; ++j) st[j] = *(const bf16x8*)(gs + j * 8);
        }
        // compute 8 16-col subtiles from Bt[cur]
        const short* B = &Bt[cur][0];
        #pragma unroll
        for (int s = 0; s < 8; ++s) {
            const int C = s * 16 + (l & 15);
            const bf16x8 b0 = *(const bf16x8*)(B + C * 64 + (g0 << 3));
            const bf16x8 b1 = *(const bf16x8*)(B + C * 64 + (g1 << 3));
            f32x4 acc = {0.0f, 0.0f, 0.0f, 0.0f};
            acc = __builtin_amdgcn_mfma_f32_16x16x32_bf16(a0, b0, acc, 0, 0, 0);
            acc = __builtin_amdgcn_mfma_f32_16x16x32_bf16(a1, b1, acc, 0, 0, 0);
            const unsigned invcol = (unsigned)(invbase - (t << 7) - (s << 4));
            #pragma unroll
            for (int r = 0; r < 4; ++r) {
                const unsigned bits = __float_as_uint(acc[r]);
                const unsigned mask = (unsigned)((int)bits >> 31) | 0x80000000u;
                const unsigned key = ((bits ^ mask) & 0xFFFFC000u) | invcol;
                ins6(keys[r], key);
            }
        }
        __syncthreads();   // Bt[cur] consumed by all waves
        if (t + 1 < 64) {
            #pragma unroll
            for (int j = 0; j < 4; ++j)
                *(bf16x8*)(&Bt[cur ^ 1][scol * 64 + (((jb + j) ^ (scol & 7)) << 3)]) = st[j];
        }
        __syncthreads();   // Bt[cur^1] ready
        cur ^= 1;
    }

    // lane's 4 acc rows are (l>>4)*4 + r within the wave's strip; 16 classes x 6 = 96/row/split
    #pragma unroll
    for (int r = 0; r < 4; ++r) {
        const int row = r0 + ((l >> 4) << 2) + r;
        int* cp = cand + ((size_t)(sp * N_NODES + row)) * 96 + (l & 15) * 6;
        #pragma unroll
        for (int t = 0; t < 6; ++t) cp[t] = 16383 - (int)(keys[r][t] & 0x3FFFu);
    }
}

// ---------------- refine2: LDS-staged exact f32-chain recompute of 192 cands -> stable top-8 ----------------
__global__ __launch_bounds__(256) void refine2_kernel(
    const float* __restrict__ F, const int* __restrict__ cand,
    float* __restrict__ resv, int* __restrict__ residx)
{
    __shared__ float sfr[64];
    __shared__ float scand[192 * 65];   // 49920 B
    __shared__ float sval[256];
    __shared__ int   sidx[256];
    const int t = threadIdx.x;
    const int row = blockIdx.x;

    if (t < 64) sfr[t] = F[(size_t)row * 64 + t];

    // stage 192 candidate rows: slot s = i*16 + (t>>4), 16 threads x float4 = 256B per row
    const int g = t >> 4, qq = t & 15;
    #pragma unroll 1
    for (int i = 0; i < 12; ++i) {
        const int s = i * 16 + g;
        const int sp = (s >= 96) ? 1 : 0;
        const int slot = s - 96 * sp;
        const int cidx = cand[((size_t)(sp * N_NODES + row)) * 96 + slot];
        const float4 v = *(const float4*)(F + ((size_t)cidx << 6) + (qq << 2));
        float* d = &scand[s * 65 + (qq << 2)];
        d[0] = v.x; d[1] = v.y; d[2] = v.z; d[3] = v.w;
    }
    __syncthreads();

    float s = -3.0e38f;
    int c = 1 << 30;
    if (t < 192) {
        const int sp = (t >= 96) ? 1 : 0;
        const int slot = t - 96 * sp;
        c = cand[((size_t)(sp * N_NODES + row)) * 96 + slot];
        const float* fp = &scand[t * 65];
        float acc = 0.0f;
        #pragma unroll 8
        for (int k = 0; k < 64; ++k) acc = fmaf(sfr[k], fp[k], acc);  // k-ascending exact chain
        s = acc;
    }
    sval[t] = s; sidx[t] = c;
    __syncthreads();

    if (t < 64) {
        float v0 = sval[t], v1 = sval[t + 64], v2 = sval[t + 128];
        int   i0 = sidx[t], i1 = sidx[t + 64], i2 = sidx[t + 128];
        #pragma unroll 1
        for (int it = 0; it < 8; ++it) {
            float bv = v0; int bi = i0;
            if (v1 > bv || (v1 == bv && i1 < bi)) { bv = v1; bi = i1; }
            if (v2 > bv || (v2 == bv && i2 < bi)) { bv = v2; bi = i2; }
            #pragma unroll
            for (int off = 32; off > 0; off >>= 1) {
                float ov = __shfl_xor(bv, off);
                int   oi = __shfl_xor(bi, off);
                if (ov > bv || (ov == bv && oi < bi)) { bv = ov; bi = oi; }
            }
            if (t == 0) {
                resv[(size_t)row * 8 + it] = bv;
                residx[(size_t)row * 8 + it] = bi;
            }
            if (i0 == bi) v0 = -3.4e38f;   // cols distinct per row
            if (i1 == bi) v1 = -3.4e38f;
            if (i2 == bi) v2 = -3.4e38f;
        }
    }
}

// ---------------- emit: FLOAT32 outputs ----------------
__global__ __launch_bounds__(256) void emit_kernel(
    const float* __restrict__ resv, const int* __restrict__ residx,
    float* __restrict__ out)
{
    const int j = blockIdx.x * 256 + threadIdx.x;
    if (j < 131072) {
        out[j] = resv[j];                             // topk_vals
    } else if (j < 262144) {
        out[j] = (float)((j - 131072) >> 3);          // new_edge_index row 0: src = slot/8
    } else {
        out[j] = (float)residx[j - 262144];           // new_edge_index row 1: topk_idx
    }
}

__global__ void canary_kernel(float* out, float code) {
    out[0] = code;
}

// ---------------- launch ----------------
extern "C" void kernel_launch(void* const* d_in, const int* in_sizes, int n_in,
                              void* d_out, int out_size, void* d_ws, size_t ws_size,
                              hipStream_t stream)
{
    const float* x   = (const float*)d_in[0];
    const void*  ei  = d_in[1];
    const float* W1  = (const float*)d_in[2];  const float* b1  = (const float*)d_in[3];
    const float* W2  = (const float*)d_in[4];  const float* b2  = (const float*)d_in[5];
    const float* W3  = (const float*)d_in[6];  const float* b3  = (const float*)d_in[7];
    const float* W4  = (const float*)d_in[8];  const float* b4  = (const float*)d_in[9];
    const float* Wg1 = (const float*)d_in[10]; const float* bg1 = (const float*)d_in[11];
    const float* Wg2 = (const float*)d_in[12]; const float* bg2 = (const float*)d_in[13];
    float* out = (float*)d_out;

    // workspace layout (stream-ordered overlays):
    //   g32   [0, 4M)
    //   F32   [4M, 8M)
    //   Fb    [8M, 10M)
    //   cand  [10M, 22M)  -- first 1.2M overlaid by CSR scratch (dead before screen):
    //       ecol_s [10M, 11M), cursor [11M, +64K), offs [11M+64K, +68K)
    //   resv  [22M, 22.5M) residx [22.5M, 23M)
    //   deg [23M, +64K) dinv [+64K, +128K) diag [+128K]
    char* ws = (char*)d_ws;
    float* g32 = (float*)(ws);
    float* F32 = (float*)(ws + ((size_t)4 << 20));
    short* Fb  = (short*)(ws + ((size_t)8 << 20));
    int*   cand   = (int*)(ws + ((size_t)10 << 20));
    int*   ecol_s = (int*)(ws + ((size_t)10 << 20));
    int*   cursor = (int*)(ws + ((size_t)11 << 20));
    int*   offs   = (int*)(ws + ((size_t)11 << 20) + (1u << 16));
    float* resv = (float*)(ws + ((size_t)22 << 20));
    int*   residx = (int*)(ws + ((size_t)22 << 20) + ((size_t)1 << 19));
    int*   deg   = (int*)(ws + ((size_t)23 << 20));
    float* dinvf = (float*)(ws + ((size_t)23 << 20) + (1u << 16));
    unsigned* diag = (unsigned*)(ws + ((size_t)23 << 20) + (2u << 16));

    const size_t NEEDED = ((size_t)23 << 20) + (2u << 16) + 256;
    if (ws_size < NEEDED || n_in < 14) {
        canary_kernel<<<1, 1, 0, stream>>>(out, ws_size < NEEDED ? 5000.0f : 3000.0f);
        return;
    }

    hipMemsetAsync(deg, 0, N_NODES * sizeof(int), stream);
    hipMemsetAsync(cursor, 0, N_NODES * sizeof(int), stream);

    detect_kernel<<<1, 64, 0, stream>>>(ei, diag);
    deg_kernel<<<E_EDGES / 256, 256, 0, stream>>>(ei, diag, deg);
    scan_kernel<<<1, 256, 0, stream>>>(deg, offs, dinvf);
    scatter_kernel<<<E_EDGES / 256, 256, 0, stream>>>(ei, diag, offs, cursor, ecol_s);
    mlp_kernel<<<N_NODES / 16, 256, 0, stream>>>(x, W1, b1, W2, b2, W3, b3, W4, b4, Wg1, bg1, Wg2, bg2, g32);
    aggcsr_kernel<<<N_NODES / 4, 256, 0, stream>>>(offs, ecol_s, dinvf, g32, F32, Fb);
    screen_kernel<<<512, 256, 0, stream>>>(Fb, cand);
    refine2_kernel<<<N_NODES, 256, 0, stream>>>(F32, cand, resv, residx);
    emit_kernel<<<(N_NODES * 24) / 256, 256, 0, stream>>>(resv, residx, out);
}

// Round 16
// 516.245 us; speedup vs baseline: 1.2368x; 1.0841x over previous
//
#include <hip/hip_runtime.h>
#include <hip/hip_bf16.h>

#define N_NODES 16384
#define E_EDGES 262144
#define IN_DIM 512

// fixed-point scale for deterministic aggregation
#define AGG_SCALE 1099511627776.0   // 2^40
#define AGG_INV   (1.0/1099511627776.0)

typedef __attribute__((ext_vector_type(8))) short bf16x8;
typedef __attribute__((ext_vector_type(4))) float f32x4;

// ---------------- edge dtype detection + access ----------------
__global__ void detect_kernel(const void* __restrict__ ei, unsigned* __restrict__ diag) {
    const unsigned long long v = ((const unsigned long long*)ei)[threadIdx.x];
    const int small = (v < 16384ull) ? 1 : 0;
    const int all64 = __all(small);
    if (threadIdx.x == 0) diag[0] = all64 ? 1u : 0u;
}

__device__ __forceinline__ int edge_at(const void* __restrict__ ei, int is64, int pos) {
    return is64 ? (int)(((const long long*)ei)[pos]) : ((const int*)ei)[pos];
}

// ---------------- degree ----------------
__global__ __launch_bounds__(256) void deg_kernel(const void* __restrict__ ei,
                                                  const unsigned* __restrict__ diag,
                                                  int* __restrict__ deg) {
    const int is64 = (int)diag[0];
    int e = blockIdx.x * 256 + threadIdx.x;
    int r = edge_at(ei, is64, e);
    if (r >= 0 && r < N_NODES) atomicAdd(&deg[r], 1);
}

// ---------------- exclusive prefix scan of deg -> offs; also dinv (fused) ----------------
__global__ __launch_bounds__(256) void scan_kernel(const int* __restrict__ deg, int* __restrict__ offs,
                                                   float* __restrict__ dinv) {
    __shared__ int part[257];
    const int t = threadIdx.x;
    const int base = t * 64;
    int s = 0;
    #pragma unroll 4
    for (int i = 0; i < 64; ++i) s += deg[base + i];
    part[t + 1] = s;
    if (t == 0) part[0] = 0;
    __syncthreads();
    if (t == 0) {
        int acc = 0;
        for (int i = 1; i <= 256; ++i) { acc += part[i]; part[i] = acc; }
    }
    __syncthreads();
    int run = part[t];                      // exclusive offset of chunk t
    for (int i = 0; i < 64; ++i) {
        const int d = deg[base + i];
        offs[base + i] = run; run += d;
        dinv[base + i] = (d > 0) ? __fdiv_rn(1.0f, __fsqrt_rn((float)d)) : 0.0f;
    }
    if (t == 255) offs[N_NODES] = run;
}

// ---------------- scatter edges into CSR slots ----------------
__global__ __launch_bounds__(256) void scatter_kernel(
    const void* __restrict__ ei, const unsigned* __restrict__ diag,
    const int* __restrict__ offs, int* __restrict__ cursor, int* __restrict__ ecol_s)
{
    const int is64 = (int)diag[0];
    int e = blockIdx.x * 256 + threadIdx.x;
    int r  = edge_at(ei, is64, e);
    if (r < 0 || r >= N_NODES) return;
    int cc = edge_at(ei, is64, E_EDGES + e);
    int pos = atomicAdd(&cursor[r], 1);
    ecol_s[offs[r] + pos] = (cc >= 0 && cc < N_NODES) ? cc : -1;
}

// ---------------- MLP: f32, k-ascending single-accumulator fmaf chains ----------------
__device__ __forceinline__ void dense_layer32(float (*hsw)[64], int c,
                                              const float* __restrict__ WP,
                                              const float* __restrict__ BP,
                                              bool relu, bool last,
                                              float* __restrict__ gout, int n0)
{
    float s0 = 0.0f, s1 = 0.0f, s2 = 0.0f, s3 = 0.0f;
    #pragma unroll 4
    for (int k = 0; k < 64; ++k) {
        const float wv = WP[k * 64 + c];
        s0 = fmaf(hsw[0][k], wv, s0);
        s1 = fmaf(hsw[1][k], wv, s1);
        s2 = fmaf(hsw[2][k], wv, s2);
        s3 = fmaf(hsw[3][k], wv, s3);
    }
    const float bv = BP[c];
    s0 += bv; s1 += bv; s2 += bv; s3 += bv;
    if (relu) { s0 = fmaxf(s0, 0.0f); s1 = fmaxf(s1, 0.0f); s2 = fmaxf(s2, 0.0f); s3 = fmaxf(s3, 0.0f); }
    __syncthreads();
    if (last) {
        gout[(size_t)(n0 + 0) * 64 + c] = s0;
        gout[(size_t)(n0 + 1) * 64 + c] = s1;
        gout[(size_t)(n0 + 2) * 64 + c] = s2;
        gout[(size_t)(n0 + 3) * 64 + c] = s3;
    } else {
        hsw[0][c] = s0; hsw[1][c] = s1; hsw[2][c] = s2; hsw[3][c] = s3;
    }
    __syncthreads();
}

__global__ __launch_bounds__(256) void mlp_kernel(
    const float* __restrict__ x,
    const float* __restrict__ W1, const float* __restrict__ b1,
    const float* __restrict__ W2, const float* __restrict__ b2,
    const float* __restrict__ W3, const float* __restrict__ b3,
    const float* __restrict__ W4, const float* __restrict__ b4,
    const float* __restrict__ Wg1, const float* __restrict__ bg1,
    const float* __restrict__ Wg2, const float* __restrict__ bg2,
    float* __restrict__ g32)
{
    __shared__ float hs[4][4][64];
    const int w = threadIdx.x >> 6;
    const int c = threadIdx.x & 63;
    const int n0 = blockIdx.x * 16 + w * 4;

    float a0 = 0.0f, a1 = 0.0f, a2 = 0.0f, a3 = 0.0f;
    const float* xp = x + (size_t)n0 * IN_DIM;
    #pragma unroll 4
    for (int k = 0; k < IN_DIM; ++k) {
        const float wv = W1[k * 64 + c];
        a0 = fmaf(xp[k],              wv, a0);
        a1 = fmaf(xp[IN_DIM + k],     wv, a1);
        a2 = fmaf(xp[2 * IN_DIM + k], wv, a2);
        a3 = fmaf(xp[3 * IN_DIM + k], wv, a3);
    }
    const float bv = b1[c];
    hs[w][0][c] = fmaxf(a0 + bv, 0.0f);
    hs[w][1][c] = fmaxf(a1 + bv, 0.0f);
    hs[w][2][c] = fmaxf(a2 + bv, 0.0f);
    hs[w][3][c] = fmaxf(a3 + bv, 0.0f);
    __syncthreads();

    dense_layer32(hs[w], c, W2, b2, false, false, g32, n0);
    dense_layer32(hs[w], c, W3, b3, true,  false, g32, n0);
    dense_layer32(hs[w], c, W4, b4, false, false, g32, n0);
    dense_layer32(hs[w], c, Wg1, bg1, true, false, g32, n0);
    dense_layer32(hs[w], c, Wg2, bg2, false, true, g32, n0);
}

// ---------------- CSR aggregation + finalize (fused): one wave per row ----------------
// unroll 4: iterations independent (integer sum) -> 4 gather chains in flight.
__global__ __launch_bounds__(256) void aggcsr_kernel(
    const int* __restrict__ offs, const int* __restrict__ ecol_s,
    const float* __restrict__ dinv, const float* __restrict__ g32,
    float* __restrict__ F32, short* __restrict__ Fb)
{
    const int r = (blockIdx.x << 2) + (threadIdx.x >> 6);
    const int h = threadIdx.x & 63;
    const float dr = dinv[r];
    const int b = offs[r], e2 = offs[r + 1];
    long long sum = 0;
    #pragma unroll 4
    for (int i = b; i < e2; ++i) {
        const int cc = ecol_s[i];
        if (cc < 0) continue;
        const float m = __fmul_rn(__fmul_rn(dr, dinv[cc]), g32[((size_t)cc << 6) + h]);
        sum += __double2ll_rn((double)m * AGG_SCALE);
    }
    const float a = (float)((double)sum * AGG_INV);
    const int idx = (r << 6) + h;
    const float f = g32[idx] - a;
    F32[idx] = f;
    __hip_bfloat16 hb = __float2bfloat16(f);
    Fb[idx] = *(short*)&hb;
}

// ---------------- MFMA bf16 screening: LDS-staged B panel shared by 4 waves ----------------
__device__ __forceinline__ void ins6(unsigned* k, unsigned x) {
    const unsigned r0 = max(k[0], x);
    k[5] = min(k[4], max(k[5], x));
    k[4] = min(k[3], max(k[4], x));
    k[3] = min(k[2], max(k[3], x));
    k[2] = min(k[1], max(k[2], x));
    k[1] = min(k[0], max(k[1], x));
    k[0] = r0;
}

__global__ __launch_bounds__(256) void screen_kernel(
    const short* __restrict__ Fb, int* __restrict__ cand)
{
    __shared__ short Bt[2][128 * 64];   // 2 x 16 KB: [buf][col*64 + swizzled k]
    const int l = threadIdx.x & 63;
    const int w = threadIdx.x >> 6;
    const int rb = blockIdx.x >> 1;
    const int sp = blockIdx.x & 1;
    const int r0 = rb * 64 + w * 16;
    const int c0 = sp * 8192;

    // A fragments: lane l <- Fb[r0 + (l&15)][8*(l>>4) .. +7] and +32
    const short* ap = Fb + ((size_t)(r0 + (l & 15)) << 6) + ((l >> 4) << 3);
    const bf16x8 a0 = *(const bf16x8*)(ap);
    const bf16x8 a1 = *(const bf16x8*)(ap + 32);

    unsigned keys[4][6];
    #pragma unroll
    for (int r = 0; r < 4; ++r)
        #pragma unroll
        for (int t = 0; t < 6; ++t) keys[r][t] = 0u;

    // staging role: col = tid&127, granules jb..jb+3 (64B of the 128B row)
    const int scol = threadIdx.x & 127;
    const int jb = (threadIdx.x >> 7) * 4;
    const short* gsrc0 = Fb + ((size_t)(c0 + scol) << 6) + jb * 8;

    // prologue: stage tile 0
    bf16x8 st[4];
    #pragma unroll
    for (int j = 0; j < 4; ++j) st[j] = *(const bf16x8*)(gsrc0 + j * 8);
    #pragma unroll
    for (int j = 0; j < 4; ++j)
        *(bf16x8*)(&Bt[0][scol * 64 + (((jb + j) ^ (scol & 7)) << 3)]) = st[j];
    __syncthreads();

    const int invbase = 16383 - c0 - (l & 15);
    const int g0 = (l >> 4) ^ (l & 7);
    const int g1 = ((l >> 4) + 4) ^ (l & 7);
    int cur = 0;

    #pragma unroll 1
    for (int t = 0; t < 64; ++t) {
        // issue next tile's global loads early (latency hides under compute)
        if (t + 1 < 64) {
            const short* gs = gsrc0 + ((size_t)(t + 1) << 13);   // +128 cols * 64 shorts
            #pragma unroll
            for (int j = 0; j < 4; ++j) st[j] = *(const bf16x8*)(gs + j * 8);
        }
        // compute 8 16-col subtiles from Bt[cur]
        const short* B = &Bt[cur][0];
        #pragma unroll
        for (int s = 0; s < 8; ++s) {
            const int C = s * 16 + (l & 15);
            const bf16x8 b0 = *(const bf16x8*)(B + C * 64 + (g0 << 3));
            const bf16x8 b1 = *(const bf16x8*)(B + C * 64 + (g1 << 3));
            f32x4 acc = {0.0f, 0.0f, 0.0f, 0.0f};
            acc = __builtin_amdgcn_mfma_f32_16x16x32_bf16(a0, b0, acc, 0, 0, 0);
            acc = __builtin_amdgcn_mfma_f32_16x16x32_bf16(a1, b1, acc, 0, 0, 0);
            const unsigned invcol = (unsigned)(invbase - (t << 7) - (s << 4));
            #pragma unroll
            for (int r = 0; r < 4; ++r) {
                const unsigned bits = __float_as_uint(acc[r]);
                const unsigned mask = (unsigned)((int)bits >> 31) | 0x80000000u;
                const unsigned key = ((bits ^ mask) & 0xFFFFC000u) | invcol;
                ins6(keys[r], key);
            }
        }
        __syncthreads();   // Bt[cur] consumed by all waves
        if (t + 1 < 64) {
            #pragma unroll
            for (int j = 0; j < 4; ++j)
                *(bf16x8*)(&Bt[cur ^ 1][scol * 64 + (((jb + j) ^ (scol & 7)) << 3)]) = st[j];
        }
        __syncthreads();   // Bt[cur^1] ready
        cur ^= 1;
    }

    // lane's 4 acc rows are (l>>4)*4 + r within the wave's strip; 16 classes x 6 = 96/row/split
    #pragma unroll
    for (int r = 0; r < 4; ++r) {
        const int row = r0 + ((l >> 4) << 2) + r;
        int* cp = cand + ((size_t)(sp * N_NODES + row)) * 96 + (l & 15) * 6;
        #pragma unroll
        for (int t = 0; t < 6; ++t) cp[t] = 16383 - (int)(keys[r][t] & 0x3FFFu);
    }
}

// ---------------- refine2: phase-split staged exact f32-chain recompute -> stable top-8 ----------------
// Stage phase pipelined: 12 independent cand-index loads, then 12 independent gathers,
// then 12 LDS writes (was a 12-deep serial dependent chain = the 211us latency wall).
__global__ __launch_bounds__(256) void refine2_kernel(
    const float* __restrict__ F, const int* __restrict__ cand,
    float* __restrict__ resv, int* __restrict__ residx)
{
    __shared__ float sfr[64];
    __shared__ float scand[192 * 65];   // 49920 B
    __shared__ float sval[256];
    __shared__ int   sidx[256];
    const int t = threadIdx.x;
    const int row = blockIdx.x;

    if (t < 64) sfr[t] = F[(size_t)row * 64 + t];

    // stage 192 candidate rows: slot s = i*16 + (t>>4), 16 threads x float4 = 256B per row
    const int g = t >> 4, qq = t & 15;
    int cidx12[12];
    #pragma unroll
    for (int i = 0; i < 12; ++i) {
        const int s = i * 16 + g;
        const int sp = (s >= 96) ? 1 : 0;
        const int slot = s - 96 * sp;
        cidx12[i] = cand[((size_t)(sp * N_NODES + row)) * 96 + slot];
    }
    float4 v12[12];
    #pragma unroll
    for (int i = 0; i < 12; ++i)
        v12[i] = *(const float4*)(F + ((size_t)cidx12[i] << 6) + (qq << 2));
    #pragma unroll
    for (int i = 0; i < 12; ++i) {
        float* d = &scand[(i * 16 + g) * 65 + (qq << 2)];
        d[0] = v12[i].x; d[1] = v12[i].y; d[2] = v12[i].z; d[3] = v12[i].w;
    }
    __syncthreads();

    float s = -3.0e38f;
    int c = 1 << 30;
    if (t < 192) {
        const int sp = (t >= 96) ? 1 : 0;
        const int slot = t - 96 * sp;
        c = cand[((size_t)(sp * N_NODES + row)) * 96 + slot];
        const float* fp = &scand[t * 65];
        float acc = 0.0f;
        #pragma unroll 8
        for (int k = 0; k < 64; ++k) acc = fmaf(sfr[k], fp[k], acc);  // k-ascending exact chain
        s = acc;
    }
    sval[t] = s; sidx[t] = c;
    __syncthreads();

    if (t < 64) {
        float v0 = sval[t], v1 = sval[t + 64], v2 = sval[t + 128];
        int   i0 = sidx[t], i1 = sidx[t + 64], i2 = sidx[t + 128];
        #pragma unroll 1
        for (int it = 0; it < 8; ++it) {
            float bv = v0; int bi = i0;
            if (v1 > bv || (v1 == bv && i1 < bi)) { bv = v1; bi = i1; }
            if (v2 > bv || (v2 == bv && i2 < bi)) { bv = v2; bi = i2; }
            #pragma unroll
            for (int off = 32; off > 0; off >>= 1) {
                float ov = __shfl_xor(bv, off);
                int   oi = __shfl_xor(bi, off);
                if (ov > bv || (ov == bv && oi < bi)) { bv = ov; bi = oi; }
            }
            if (t == 0) {
                resv[(size_t)row * 8 + it] = bv;
                residx[(size_t)row * 8 + it] = bi;
            }
            if (i0 == bi) v0 = -3.4e38f;   // cols distinct per row
            if (i1 == bi) v1 = -3.4e38f;
            if (i2 == bi) v2 = -3.4e38f;
        }
    }
}

// ---------------- emit: FLOAT32 outputs ----------------
__global__ __launch_bounds__(256) void emit_kernel(
    const float* __restrict__ resv, const int* __restrict__ residx,
    float* __restrict__ out)
{
    const int j = blockIdx.x * 256 + threadIdx.x;
    if (j < 131072) {
        out[j] = resv[j];                             // topk_vals
    } else if (j < 262144) {
        out[j] = (float)((j - 131072) >> 3);          // new_edge_index row 0: src = slot/8
    } else {
        out[j] = (float)residx[j - 262144];           // new_edge_index row 1: topk_idx
    }
}

__global__ void canary_kernel(float* out, float code) {
    out[0] = code;
}

// ---------------- launch ----------------
extern "C" void kernel_launch(void* const* d_in, const int* in_sizes, int n_in,
                              void* d_out, int out_size, void* d_ws, size_t ws_size,
                              hipStream_t stream)
{
    const float* x   = (const float*)d_in[0];
    const void*  ei  = d_in[1];
    const float* W1  = (const float*)d_in[2];  const float* b1  = (const float*)d_in[3];
    const float* W2  = (const float*)d_in[4];  const float* b2  = (const float*)d_in[5];
    const float* W3  = (const float*)d_in[6];  const float* b3  = (const float*)d_in[7];
    const float* W4  = (const float*)d_in[8];  const float* b4  = (const float*)d_in[9];
    const float* Wg1 = (const float*)d_in[10]; const float* bg1 = (const float*)d_in[11];
    const float* Wg2 = (const float*)d_in[12]; const float* bg2 = (const float*)d_in[13];
    float* out = (float*)d_out;

    // workspace layout (stream-ordered overlays):
    //   g32   [0, 4M)
    //   F32   [4M, 8M)
    //   Fb    [8M, 10M)
    //   cand  [10M, 22M)  -- first 1.2M overlaid by CSR scratch (dead before screen):
    //       ecol_s [10M, 11M), cursor [11M, +64K), offs [11M+64K, +68K)
    //   resv  [22M, 22.5M) residx [22.5M, 23M)
    //   deg [23M, +64K) dinv [+64K, +128K) diag [+128K]
    char* ws = (char*)d_ws;
    float* g32 = (float*)(ws);
    float* F32 = (float*)(ws + ((size_t)4 << 20));
    short* Fb  = (short*)(ws + ((size_t)8 << 20));
    int*   cand   = (int*)(ws + ((size_t)10 << 20));
    int*   ecol_s = (int*)(ws + ((size_t)10 << 20));
    int*   cursor = (int*)(ws + ((size_t)11 << 20));
    int*   offs   = (int*)(ws + ((size_t)11 << 20) + (1u << 16));
    float* resv = (float*)(ws + ((size_t)22 << 20));
    int*   residx = (int*)(ws + ((size_t)22 << 20) + ((size_t)1 << 19));
    int*   deg   = (int*)(ws + ((size_t)23 << 20));
    float* dinvf = (float*)(ws + ((size_t)23 << 20) + (1u << 16));
    unsigned* diag = (unsigned*)(ws + ((size_t)23 << 20) + (2u << 16));

    const size_t NEEDED = ((size_t)23 << 20) + (2u << 16) + 256;
    if (ws_size < NEEDED || n_in < 14) {
        canary_kernel<<<1, 1, 0, stream>>>(out, ws_size < NEEDED ? 5000.0f : 3000.0f);
        return;
    }

    hipMemsetAsync(deg, 0, N_NODES * sizeof(int), stream);
    hipMemsetAsync(cursor, 0, N_NODES * sizeof(int), stream);

    detect_kernel<<<1, 64, 0, stream>>>(ei, diag);
    deg_kernel<<<E_EDGES / 256, 256, 0, stream>>>(ei, diag, deg);
    scan_kernel<<<1, 256, 0, stream>>>(deg, offs, dinvf);
    scatter_kernel<<<E_EDGES / 256, 256, 0, stream>>>(ei, diag, offs, cursor, ecol_s);
    mlp_kernel<<<N_NODES / 16, 256, 0, stream>>>(x, W1, b1, W2, b2, W3, b3, W4, b4, Wg1, bg1, Wg2, bg2, g32);
    aggcsr_kernel<<<N_NODES / 4, 256, 0, stream>>>(offs, ecol_s, dinvf, g32, F32, Fb);
    screen_kernel<<<512, 256, 0, stream>>>(Fb, cand);
    refine2_kernel<<<N_NODES, 256, 0, stream>>>(F32, cand, resv, residx);
    emit_kernel<<<(N_NODES * 24) / 256, 256, 0, stream>>>(resv, residx, out);
}

// Round 17
// 509.725 us; speedup vs baseline: 1.2526x; 1.0128x over previous
//
#include <hip/hip_runtime.h>
#include <hip/hip_bf16.h>

#define N_NODES 16384
#define E_EDGES 262144
#define IN_DIM 512

// fixed-point scale for deterministic aggregation
#define AGG_SCALE 1099511627776.0   // 2^40
#define AGG_INV   (1.0/1099511627776.0)

typedef __attribute__((ext_vector_type(8))) short bf16x8;
typedef __attribute__((ext_vector_type(4))) float f32x4;

// ---------------- edge dtype detection + access ----------------
__global__ void detect_kernel(const void* __restrict__ ei, unsigned* __restrict__ diag) {
    const unsigned long long v = ((const unsigned long long*)ei)[threadIdx.x];
    const int small = (v < 16384ull) ? 1 : 0;
    const int all64 = __all(small);
    if (threadIdx.x == 0) diag[0] = all64 ? 1u : 0u;
}

__device__ __forceinline__ int edge_at(const void* __restrict__ ei, int is64, int pos) {
    return is64 ? (int)(((const long long*)ei)[pos]) : ((const int*)ei)[pos];
}

// ---------------- degree ----------------
__global__ __launch_bounds__(256) void deg_kernel(const void* __restrict__ ei,
                                                  const unsigned* __restrict__ diag,
                                                  int* __restrict__ deg) {
    const int is64 = (int)diag[0];
    int e = blockIdx.x * 256 + threadIdx.x;
    int r = edge_at(ei, is64, e);
    if (r >= 0 && r < N_NODES) atomicAdd(&deg[r], 1);
}

// ---------------- exclusive prefix scan of deg -> offs; also dinv (fused) ----------------
__global__ __launch_bounds__(256) void scan_kernel(const int* __restrict__ deg, int* __restrict__ offs,
                                                   float* __restrict__ dinv) {
    __shared__ int part[257];
    const int t = threadIdx.x;
    const int base = t * 64;
    int s = 0;
    #pragma unroll 4
    for (int i = 0; i < 64; ++i) s += deg[base + i];
    part[t + 1] = s;
    if (t == 0) part[0] = 0;
    __syncthreads();
    if (t == 0) {
        int acc = 0;
        for (int i = 1; i <= 256; ++i) { acc += part[i]; part[i] = acc; }
    }
    __syncthreads();
    int run = part[t];                      // exclusive offset of chunk t
    for (int i = 0; i < 64; ++i) {
        const int d = deg[base + i];
        offs[base + i] = run; run += d;
        dinv[base + i] = (d > 0) ? __fdiv_rn(1.0f, __fsqrt_rn((float)d)) : 0.0f;
    }
    if (t == 255) offs[N_NODES] = run;
}

// ---------------- scatter edges into CSR slots ----------------
__global__ __launch_bounds__(256) void scatter_kernel(
    const void* __restrict__ ei, const unsigned* __restrict__ diag,
    const int* __restrict__ offs, int* __restrict__ cursor, int* __restrict__ ecol_s)
{
    const int is64 = (int)diag[0];
    int e = blockIdx.x * 256 + threadIdx.x;
    int r  = edge_at(ei, is64, e);
    if (r < 0 || r >= N_NODES) return;
    int cc = edge_at(ei, is64, E_EDGES + e);
    int pos = atomicAdd(&cursor[r], 1);
    ecol_s[offs[r] + pos] = (cc >= 0 && cc < N_NODES) ? cc : -1;
}

// ---------------- MLP: f32, k-ascending single-accumulator fmaf chains ----------------
__device__ __forceinline__ void dense_layer32(float (*hsw)[64], int c,
                                              const float* __restrict__ WP,
                                              const float* __restrict__ BP,
                                              bool relu, bool last,
                                              float* __restrict__ gout, int n0)
{
    float s0 = 0.0f, s1 = 0.0f, s2 = 0.0f, s3 = 0.0f;
    #pragma unroll 4
    for (int k = 0; k < 64; ++k) {
        const float wv = WP[k * 64 + c];
        s0 = fmaf(hsw[0][k], wv, s0);
        s1 = fmaf(hsw[1][k], wv, s1);
        s2 = fmaf(hsw[2][k], wv, s2);
        s3 = fmaf(hsw[3][k], wv, s3);
    }
    const float bv = BP[c];
    s0 += bv; s1 += bv; s2 += bv; s3 += bv;
    if (relu) { s0 = fmaxf(s0, 0.0f); s1 = fmaxf(s1, 0.0f); s2 = fmaxf(s2, 0.0f); s3 = fmaxf(s3, 0.0f); }
    __syncthreads();
    if (last) {
        gout[(size_t)(n0 + 0) * 64 + c] = s0;
        gout[(size_t)(n0 + 1) * 64 + c] = s1;
        gout[(size_t)(n0 + 2) * 64 + c] = s2;
        gout[(size_t)(n0 + 3) * 64 + c] = s3;
    } else {
        hsw[0][c] = s0; hsw[1][c] = s1; hsw[2][c] = s2; hsw[3][c] = s3;
    }
    __syncthreads();
}

__global__ __launch_bounds__(256) void mlp_kernel(
    const float* __restrict__ x,
    const float* __restrict__ W1, const float* __restrict__ b1,
    const float* __restrict__ W2, const float* __restrict__ b2,
    const float* __restrict__ W3, const float* __restrict__ b3,
    const float* __restrict__ W4, const float* __restrict__ b4,
    const float* __restrict__ Wg1, const float* __restrict__ bg1,
    const float* __restrict__ Wg2, const float* __restrict__ bg2,
    float* __restrict__ g32)
{
    __shared__ float hs[4][4][64];
    const int w = threadIdx.x >> 6;
    const int c = threadIdx.x & 63;
    const int n0 = blockIdx.x * 16 + w * 4;

    float a0 = 0.0f, a1 = 0.0f, a2 = 0.0f, a3 = 0.0f;
    const float* xp = x + (size_t)n0 * IN_DIM;
    #pragma unroll 4
    for (int k = 0; k < IN_DIM; ++k) {
        const float wv = W1[k * 64 + c];
        a0 = fmaf(xp[k],              wv, a0);
        a1 = fmaf(xp[IN_DIM + k],     wv, a1);
        a2 = fmaf(xp[2 * IN_DIM + k], wv, a2);
        a3 = fmaf(xp[3 * IN_DIM + k], wv, a3);
    }
    const float bv = b1[c];
    hs[w][0][c] = fmaxf(a0 + bv, 0.0f);
    hs[w][1][c] = fmaxf(a1 + bv, 0.0f);
    hs[w][2][c] = fmaxf(a2 + bv, 0.0f);
    hs[w][3][c] = fmaxf(a3 + bv, 0.0f);
    __syncthreads();

    dense_layer32(hs[w], c, W2, b2, false, false, g32, n0);
    dense_layer32(hs[w], c, W3, b3, true,  false, g32, n0);
    dense_layer32(hs[w], c, W4, b4, false, false, g32, n0);
    dense_layer32(hs[w], c, Wg1, bg1, true, false, g32, n0);
    dense_layer32(hs[w], c, Wg2, bg2, false, true, g32, n0);
}

// ---------------- CSR aggregation + finalize (fused): one wave per row ----------------
// unroll 8 (avg deg 16): gather chains ~2 deep.
__global__ __launch_bounds__(256) void aggcsr_kernel(
    const int* __restrict__ offs, const int* __restrict__ ecol_s,
    const float* __restrict__ dinv, const float* __restrict__ g32,
    float* __restrict__ F32, short* __restrict__ Fb)
{
    const int r = (blockIdx.x << 2) + (threadIdx.x >> 6);
    const int h = threadIdx.x & 63;
    const float dr = dinv[r];
    const int b = offs[r], e2 = offs[r + 1];
    long long sum = 0;
    #pragma unroll 8
    for (int i = b; i < e2; ++i) {
        const int cc = ecol_s[i];
        if (cc < 0) continue;
        const float m = __fmul_rn(__fmul_rn(dr, dinv[cc]), g32[((size_t)cc << 6) + h]);
        sum += __double2ll_rn((double)m * AGG_SCALE);
    }
    const float a = (float)((double)sum * AGG_INV);
    const int idx = (r << 6) + h;
    const float f = g32[idx] - a;
    F32[idx] = f;
    __hip_bfloat16 hb = __float2bfloat16(f);
    Fb[idx] = *(short*)&hb;
}

// ---------------- MFMA bf16 screening: LDS-staged B panel shared by 4 waves ----------------
__device__ __forceinline__ void ins6(unsigned* k, unsigned x) {
    const unsigned r0 = max(k[0], x);
    k[5] = min(k[4], max(k[5], x));
    k[4] = min(k[3], max(k[4], x));
    k[3] = min(k[2], max(k[3], x));
    k[2] = min(k[1], max(k[2], x));
    k[1] = min(k[0], max(k[1], x));
    k[0] = r0;
}

__global__ __launch_bounds__(256) void screen_kernel(
    const short* __restrict__ Fb, int* __restrict__ cand)
{
    __shared__ short Bt[2][128 * 64];   // 2 x 16 KB: [buf][col*64 + swizzled k]
    const int l = threadIdx.x & 63;
    const int w = threadIdx.x >> 6;
    const int rb = blockIdx.x >> 1;
    const int sp = blockIdx.x & 1;
    const int r0 = rb * 64 + w * 16;
    const int c0 = sp * 8192;

    // A fragments: lane l <- Fb[r0 + (l&15)][8*(l>>4) .. +7] and +32
    const short* ap = Fb + ((size_t)(r0 + (l & 15)) << 6) + ((l >> 4) << 3);
    const bf16x8 a0 = *(const bf16x8*)(ap);
    const bf16x8 a1 = *(const bf16x8*)(ap + 32);

    unsigned keys[4][6];
    #pragma unroll
    for (int r = 0; r < 4; ++r)
        #pragma unroll
        for (int t = 0; t < 6; ++t) keys[r][t] = 0u;

    // staging role: col = tid&127, granules jb..jb+3 (64B of the 128B row)
    const int scol = threadIdx.x & 127;
    const int jb = (threadIdx.x >> 7) * 4;
    const short* gsrc0 = Fb + ((size_t)(c0 + scol) << 6) + jb * 8;

    // prologue: stage tile 0
    bf16x8 st[4];
    #pragma unroll
    for (int j = 0; j < 4; ++j) st[j] = *(const bf16x8*)(gsrc0 + j * 8);
    #pragma unroll
    for (int j = 0; j < 4; ++j)
        *(bf16x8*)(&Bt[0][scol * 64 + (((jb + j) ^ (scol & 7)) << 3)]) = st[j];
    __syncthreads();

    const int invbase = 16383 - c0 - (l & 15);
    const int g0 = (l >> 4) ^ (l & 7);
    const int g1 = ((l >> 4) + 4) ^ (l & 7);
    int cur = 0;

    #pragma unroll 1
    for (int t = 0; t < 64; ++t) {
        // issue next tile's global loads early (latency hides under compute)
        if (t + 1 < 64) {
            const short* gs = gsrc0 + ((size_t)(t + 1) << 13);   // +128 cols * 64 shorts
            #pragma unroll
            for (int j = 0; j < 4; ++j) st[j] = *(const bf16x8*)(gs + j * 8);
        }
        // hoist ALL b-fragment LDS reads for the tile (16 independent ds_read_b128)
        const short* B = &Bt[cur][0];
        bf16x8 bf[16];
        #pragma unroll
        for (int s = 0; s < 8; ++s) {
            const int C = s * 16 + (l & 15);
            bf[2 * s]     = *(const bf16x8*)(B + C * 64 + (g0 << 3));
            bf[2 * s + 1] = *(const bf16x8*)(B + C * 64 + (g1 << 3));
        }
        // 8 independent {2 MFMA + maintenance} chains
        #pragma unroll
        for (int s = 0; s < 8; ++s) {
            f32x4 acc = {0.0f, 0.0f, 0.0f, 0.0f};
            acc = __builtin_amdgcn_mfma_f32_16x16x32_bf16(a0, bf[2 * s], acc, 0, 0, 0);
            acc = __builtin_amdgcn_mfma_f32_16x16x32_bf16(a1, bf[2 * s + 1], acc, 0, 0, 0);
            const unsigned invcol = (unsigned)(invbase - (t << 7) - (s << 4));
            #pragma unroll
            for (int r = 0; r < 4; ++r) {
                const unsigned bits = __float_as_uint(acc[r]);
                const unsigned mask = (unsigned)((int)bits >> 31) | 0x80000000u;
                const unsigned key = ((bits ^ mask) & 0xFFFFC000u) | invcol;
                ins6(keys[r], key);
            }
        }
        __syncthreads();   // Bt[cur] consumed by all waves
        if (t + 1 < 64) {
            #pragma unroll
            for (int j = 0; j < 4; ++j)
                *(bf16x8*)(&Bt[cur ^ 1][scol * 64 + (((jb + j) ^ (scol & 7)) << 3)]) = st[j];
        }
        __syncthreads();   // Bt[cur^1] ready
        cur ^= 1;
    }

    // lane's 4 acc rows are (l>>4)*4 + r within the wave's strip; 16 classes x 6 = 96/row/split
    #pragma unroll
    for (int r = 0; r < 4; ++r) {
        const int row = r0 + ((l >> 4) << 2) + r;
        int* cp = cand + ((size_t)(sp * N_NODES + row)) * 96 + (l & 15) * 6;
        #pragma unroll
        for (int t = 0; t < 6; ++t) cp[t] = 16383 - (int)(keys[r][t] & 0x3FFFu);
    }
}

// ---------------- refine2: 512-thread, 6-deep phase-split staging; writes out directly ----------------
__global__ __launch_bounds__(512) void refine2_kernel(
    const float* __restrict__ F, const int* __restrict__ cand,
    float* __restrict__ out)
{
    __shared__ float sfr[64];
    __shared__ float scand[192 * 65];   // 49920 B
    __shared__ float sval[192];
    __shared__ int   sidx[192];
    const int t = threadIdx.x;
    const int row = blockIdx.x;

    if (t < 64) sfr[t] = F[(size_t)row * 64 + t];

    // stage 192 candidate rows: 32 groups x 6 slots, 16 threads x float4 = 256B per row
    const int g = t >> 4, qq = t & 15;   // g in 0..31
    int cidx6[6];
    #pragma unroll
    for (int i = 0; i < 6; ++i) {
        const int s = i * 32 + g;
        const int sp = (s >= 96) ? 1 : 0;
        const int slot = s - 96 * sp;
        cidx6[i] = cand[((size_t)(sp * N_NODES + row)) * 96 + slot];
    }
    float4 v6[6];
    #pragma unroll
    for (int i = 0; i < 6; ++i)
        v6[i] = *(const float4*)(F + ((size_t)cidx6[i] << 6) + (qq << 2));
    #pragma unroll
    for (int i = 0; i < 6; ++i) {
        float* d = &scand[(i * 32 + g) * 65 + (qq << 2)];
        d[0] = v6[i].x; d[1] = v6[i].y; d[2] = v6[i].z; d[3] = v6[i].w;
    }
    __syncthreads();

    if (t < 192) {
        const int sp = (t >= 96) ? 1 : 0;
        const int slot = t - 96 * sp;
        const int c = cand[((size_t)(sp * N_NODES + row)) * 96 + slot];
        const float* fp = &scand[t * 65];
        float acc = 0.0f;
        #pragma unroll 8
        for (int k = 0; k < 64; ++k) acc = fmaf(sfr[k], fp[k], acc);  // k-ascending exact chain
        sval[t] = acc; sidx[t] = c;
    }
    __syncthreads();

    if (t < 64) {
        float v0 = sval[t], v1 = sval[t + 64], v2 = sval[t + 128];
        int   i0 = sidx[t], i1 = sidx[t + 64], i2 = sidx[t + 128];
        #pragma unroll 1
        for (int it = 0; it < 8; ++it) {
            float bv = v0; int bi = i0;
            if (v1 > bv || (v1 == bv && i1 < bi)) { bv = v1; bi = i1; }
            if (v2 > bv || (v2 == bv && i2 < bi)) { bv = v2; bi = i2; }
            #pragma unroll
            for (int off = 32; off > 0; off >>= 1) {
                float ov = __shfl_xor(bv, off);
                int   oi = __shfl_xor(bi, off);
                if (ov > bv || (ov == bv && oi < bi)) { bv = ov; bi = oi; }
            }
            if (t == 0) {
                out[(size_t)row * 8 + it]          = bv;          // topk_vals
                out[131072 + (size_t)row * 8 + it] = (float)row;  // new_edge_index row 0
                out[262144 + (size_t)row * 8 + it] = (float)bi;   // new_edge_index row 1
            }
            if (i0 == bi) v0 = -3.4e38f;   // cols distinct per row
            if (i1 == bi) v1 = -3.4e38f;
            if (i2 == bi) v2 = -3.4e38f;
        }
    }
}

__global__ void canary_kernel(float* out, float code) {
    out[0] = code;
}

// ---------------- launch ----------------
extern "C" void kernel_launch(void* const* d_in, const int* in_sizes, int n_in,
                              void* d_out, int out_size, void* d_ws, size_t ws_size,
                              hipStream_t stream)
{
    const float* x   = (const float*)d_in[0];
    const void*  ei  = d_in[1];
    const float* W1  = (const float*)d_in[2];  const float* b1  = (const float*)d_in[3];
    const float* W2  = (const float*)d_in[4];  const float* b2  = (const float*)d_in[5];
    const float* W3  = (const float*)d_in[6];  const float* b3  = (const float*)d_in[7];
    const float* W4  = (const float*)d_in[8];  const float* b4  = (const float*)d_in[9];
    const float* Wg1 = (const float*)d_in[10]; const float* bg1 = (const float*)d_in[11];
    const float* Wg2 = (const float*)d_in[12]; const float* bg2 = (const float*)d_in[13];
    float* out = (float*)d_out;

    // workspace layout (stream-ordered overlays):
    //   g32   [0, 4M)
    //   F32   [4M, 8M)
    //   Fb    [8M, 10M)
    //   cand  [10M, 22M)  -- first 1.2M overlaid by CSR scratch (dead before screen):
    //       ecol_s [10M, 11M), cursor [11M, +64K), offs [11M+64K, +68K)
    //   deg [23M, +64K) dinv [+64K, +128K) diag [+128K]
    char* ws = (char*)d_ws;
    float* g32 = (float*)(ws);
    float* F32 = (float*)(ws + ((size_t)4 << 20));
    short* Fb  = (short*)(ws + ((size_t)8 << 20));
    int*   cand   = (int*)(ws + ((size_t)10 << 20));
    int*   ecol_s = (int*)(ws + ((size_t)10 << 20));
    int*   cursor = (int*)(ws + ((size_t)11 << 20));
    int*   offs   = (int*)(ws + ((size_t)11 << 20) + (1u << 16));
    int*   deg   = (int*)(ws + ((size_t)23 << 20));
    float* dinvf = (float*)(ws + ((size_t)23 << 20) + (1u << 16));
    unsigned* diag = (unsigned*)(ws + ((size_t)23 << 20) + (2u << 16));

    const size_t NEEDED = ((size_t)23 << 20) + (2u << 16) + 256;
    if (ws_size < NEEDED || n_in < 14) {
        canary_kernel<<<1, 1, 0, stream>>>(out, ws_size < NEEDED ? 5000.0f : 3000.0f);
        return;
    }

    hipMemsetAsync(deg, 0, N_NODES * sizeof(int), stream);
    hipMemsetAsync(cursor, 0, N_NODES * sizeof(int), stream);

    detect_kernel<<<1, 64, 0, stream>>>(ei, diag);
    deg_kernel<<<E_EDGES / 256, 256, 0, stream>>>(ei, diag, deg);
    scan_kernel<<<1, 256, 0, stream>>>(deg, offs, dinvf);
    scatter_kernel<<<E_EDGES / 256, 256, 0, stream>>>(ei, diag, offs, cursor, ecol_s);
    mlp_kernel<<<N_NODES / 16, 256, 0, stream>>>(x, W1, b1, W2, b2, W3, b3, W4, b4, Wg1, bg1, Wg2, bg2, g32);
    aggcsr_kernel<<<N_NODES / 4, 256, 0, stream>>>(offs, ecol_s, dinvf, g32, F32, Fb);
    screen_kernel<<<512, 256, 0, stream>>>(Fb, cand);
    refine2_kernel<<<N_NODES, 512, 0, stream>>>(F32, cand, out);
}

// Round 18
// 475.501 us; speedup vs baseline: 1.3427x; 1.0720x over previous
//
#include <hip/hip_runtime.h>
#include <hip/hip_bf16.h>

#define N_NODES 16384
#define E_EDGES 262144
#define IN_DIM 512

// fixed-point scale for deterministic aggregation
#define AGG_SCALE 1099511627776.0   // 2^40
#define AGG_INV   (1.0/1099511627776.0)

typedef __attribute__((ext_vector_type(8))) short bf16x8;
typedef __attribute__((ext_vector_type(4))) float f32x4;

// ---------------- inline edge dtype detection (per-wave uniform) ----------------
__device__ __forceinline__ int detect64(const void* __restrict__ ei) {
    const unsigned long long v = ((const unsigned long long*)ei)[threadIdx.x & 63];
    return __all(v < 16384ull) ? 1 : 0;
}

__device__ __forceinline__ int edge_at(const void* __restrict__ ei, int is64, int pos) {
    return is64 ? (int)(((const long long*)ei)[pos]) : ((const int*)ei)[pos];
}

// ---------------- degree ----------------
__global__ __launch_bounds__(256) void deg_kernel(const void* __restrict__ ei,
                                                  int* __restrict__ deg) {
    const int is64 = detect64(ei);
    int e = blockIdx.x * 256 + threadIdx.x;
    int r = edge_at(ei, is64, e);
    if (r >= 0 && r < N_NODES) atomicAdd(&deg[r], 1);
}

// ---------------- exclusive prefix scan of deg -> offs; also dinv (fused) ----------------
__global__ __launch_bounds__(256) void scan_kernel(const int* __restrict__ deg, int* __restrict__ offs,
                                                   float* __restrict__ dinv) {
    __shared__ int part[257];
    const int t = threadIdx.x;
    const int base = t * 64;
    int s = 0;
    #pragma unroll 4
    for (int i = 0; i < 64; ++i) s += deg[base + i];
    part[t + 1] = s;
    if (t == 0) part[0] = 0;
    __syncthreads();
    if (t == 0) {
        int acc = 0;
        for (int i = 1; i <= 256; ++i) { acc += part[i]; part[i] = acc; }
    }
    __syncthreads();
    int run = part[t];                      // exclusive offset of chunk t
    for (int i = 0; i < 64; ++i) {
        const int d = deg[base + i];
        offs[base + i] = run; run += d;
        dinv[base + i] = (d > 0) ? __fdiv_rn(1.0f, __fsqrt_rn((float)d)) : 0.0f;
    }
    if (t == 255) offs[N_NODES] = run;
}

// ---------------- scatter edges into CSR slots ----------------
__global__ __launch_bounds__(256) void scatter_kernel(
    const void* __restrict__ ei,
    const int* __restrict__ offs, int* __restrict__ cursor, int* __restrict__ ecol_s)
{
    const int is64 = detect64(ei);
    int e = blockIdx.x * 256 + threadIdx.x;
    int r  = edge_at(ei, is64, e);
    if (r < 0 || r >= N_NODES) return;
    int cc = edge_at(ei, is64, E_EDGES + e);
    int pos = atomicAdd(&cursor[r], 1);
    ecol_s[offs[r] + pos] = (cc >= 0 && cc < N_NODES) ? cc : -1;
}

// ---------------- MLP: f32, k-ascending single-accumulator fmaf chains ----------------
__device__ __forceinline__ void dense_layer32(float (*hsw)[64], int c,
                                              const float* __restrict__ WP,
                                              const float* __restrict__ BP,
                                              bool relu, bool last,
                                              float* __restrict__ gout, int n0)
{
    float s0 = 0.0f, s1 = 0.0f, s2 = 0.0f, s3 = 0.0f;
    #pragma unroll 4
    for (int k = 0; k < 64; ++k) {
        const float wv = WP[k * 64 + c];
        s0 = fmaf(hsw[0][k], wv, s0);
        s1 = fmaf(hsw[1][k], wv, s1);
        s2 = fmaf(hsw[2][k], wv, s2);
        s3 = fmaf(hsw[3][k], wv, s3);
    }
    const float bv = BP[c];
    s0 += bv; s1 += bv; s2 += bv; s3 += bv;
    if (relu) { s0 = fmaxf(s0, 0.0f); s1 = fmaxf(s1, 0.0f); s2 = fmaxf(s2, 0.0f); s3 = fmaxf(s3, 0.0f); }
    __syncthreads();
    if (last) {
        gout[(size_t)(n0 + 0) * 64 + c] = s0;
        gout[(size_t)(n0 + 1) * 64 + c] = s1;
        gout[(size_t)(n0 + 2) * 64 + c] = s2;
        gout[(size_t)(n0 + 3) * 64 + c] = s3;
    } else {
        hsw[0][c] = s0; hsw[1][c] = s1; hsw[2][c] = s2; hsw[3][c] = s3;
    }
    __syncthreads();
}

__global__ __launch_bounds__(256) void mlp_kernel(
    const float* __restrict__ x,
    const float* __restrict__ W1, const float* __restrict__ b1,
    const float* __restrict__ W2, const float* __restrict__ b2,
    const float* __restrict__ W3, const float* __restrict__ b3,
    const float* __restrict__ W4, const float* __restrict__ b4,
    const float* __restrict__ Wg1, const float* __restrict__ bg1,
    const float* __restrict__ Wg2, const float* __restrict__ bg2,
    float* __restrict__ g32)
{
    __shared__ float hs[4][4][64];
    const int w = threadIdx.x >> 6;
    const int c = threadIdx.x & 63;
    const int n0 = blockIdx.x * 16 + w * 4;

    float a0 = 0.0f, a1 = 0.0f, a2 = 0.0f, a3 = 0.0f;
    const float* xp = x + (size_t)n0 * IN_DIM;
    #pragma unroll 4
    for (int k = 0; k < IN_DIM; ++k) {
        const float wv = W1[k * 64 + c];
        a0 = fmaf(xp[k],              wv, a0);
        a1 = fmaf(xp[IN_DIM + k],     wv, a1);
        a2 = fmaf(xp[2 * IN_DIM + k], wv, a2);
        a3 = fmaf(xp[3 * IN_DIM + k], wv, a3);
    }
    const float bv = b1[c];
    hs[w][0][c] = fmaxf(a0 + bv, 0.0f);
    hs[w][1][c] = fmaxf(a1 + bv, 0.0f);
    hs[w][2][c] = fmaxf(a2 + bv, 0.0f);
    hs[w][3][c] = fmaxf(a3 + bv, 0.0f);
    __syncthreads();

    dense_layer32(hs[w], c, W2, b2, false, false, g32, n0);
    dense_layer32(hs[w], c, W3, b3, true,  false, g32, n0);
    dense_layer32(hs[w], c, W4, b4, false, false, g32, n0);
    dense_layer32(hs[w], c, Wg1, bg1, true, false, g32, n0);
    dense_layer32(hs[w], c, Wg2, bg2, false, true, g32, n0);
}

// ---------------- CSR aggregation + finalize (fused): one wave per row ----------------
__global__ __launch_bounds__(256) void aggcsr_kernel(
    const int* __restrict__ offs, const int* __restrict__ ecol_s,
    const float* __restrict__ dinv, const float* __restrict__ g32,
    float* __restrict__ F32, short* __restrict__ Fb)
{
    const int r = (blockIdx.x << 2) + (threadIdx.x >> 6);
    const int h = threadIdx.x & 63;
    const float dr = dinv[r];
    const int b = offs[r], e2 = offs[r + 1];
    long long sum = 0;
    #pragma unroll 8
    for (int i = b; i < e2; ++i) {
        const int cc = ecol_s[i];
        if (cc < 0) continue;
        const float m = __fmul_rn(__fmul_rn(dr, dinv[cc]), g32[((size_t)cc << 6) + h]);
        sum += __double2ll_rn((double)m * AGG_SCALE);
    }
    const float a = (float)((double)sum * AGG_INV);
    const int idx = (r << 6) + h;
    const float f = g32[idx] - a;
    F32[idx] = f;
    __hip_bfloat16 hb = __float2bfloat16(f);
    Fb[idx] = *(short*)&hb;
}

// ---------------- MFMA bf16 screening: LDS-staged B panel, single-barrier pipeline ----------------
// Key: ((bits ^ 0x80000000) & 0xFFFFC000) | (16383 - col). Positives order-exact;
// negatives all sort below positives (mis-order among negatives is irrelevant: a true
// top-8 sim is never negative with 16384 sims/row incl. the nonneg diagonal).
__device__ __forceinline__ void ins6(unsigned* k, unsigned x) {
    const unsigned r0 = max(k[0], x);
    k[5] = min(k[4], max(k[5], x));
    k[4] = min(k[3], max(k[4], x));
    k[3] = min(k[2], max(k[3], x));
    k[2] = min(k[1], max(k[2], x));
    k[1] = min(k[0], max(k[1], x));
    k[0] = r0;
}

__global__ __launch_bounds__(256) void screen_kernel(
    const short* __restrict__ Fb, int* __restrict__ cand)
{
    __shared__ short Bt[2][128 * 64];   // 2 x 16 KB: [buf][col*64 + swizzled k]
    const int l = threadIdx.x & 63;
    const int w = threadIdx.x >> 6;
    const int rb = blockIdx.x >> 1;
    const int sp = blockIdx.x & 1;
    const int r0 = rb * 64 + w * 16;
    const int c0 = sp * 8192;

    // A fragments: lane l <- Fb[r0 + (l&15)][8*(l>>4) .. +7] and +32
    const short* ap = Fb + ((size_t)(r0 + (l & 15)) << 6) + ((l >> 4) << 3);
    const bf16x8 a0 = *(const bf16x8*)(ap);
    const bf16x8 a1 = *(const bf16x8*)(ap + 32);

    unsigned keys[4][6];
    #pragma unroll
    for (int r = 0; r < 4; ++r)
        #pragma unroll
        for (int t = 0; t < 6; ++t) keys[r][t] = 0u;

    // staging role: col = tid&127, granules jb..jb+3 (64B of the 128B row)
    const int scol = threadIdx.x & 127;
    const int jb = (threadIdx.x >> 7) * 4;
    const short* gsrc0 = Fb + ((size_t)(c0 + scol) << 6) + jb * 8;

    // prologue: stage tile 0; preload tile 1 into st
    bf16x8 st[4];
    #pragma unroll
    for (int j = 0; j < 4; ++j) st[j] = *(const bf16x8*)(gsrc0 + j * 8);
    #pragma unroll
    for (int j = 0; j < 4; ++j)
        *(bf16x8*)(&Bt[0][scol * 64 + (((jb + j) ^ (scol & 7)) << 3)]) = st[j];
    #pragma unroll
    for (int j = 0; j < 4; ++j) st[j] = *(const bf16x8*)(gsrc0 + (1 << 13) + j * 8);
    __syncthreads();

    const int invbase = 16383 - c0 - (l & 15);
    const int g0 = (l >> 4) ^ (l & 7);
    const int g1 = ((l >> 4) + 4) ^ (l & 7);
    int cur = 0;

    #pragma unroll 1
    for (int t = 0; t < 64; ++t) {
        // hoist ALL b-fragment LDS reads for tile t (16 independent ds_read_b128)
        const short* B = &Bt[cur][0];
        bf16x8 bf[16];
        #pragma unroll
        for (int s = 0; s < 8; ++s) {
            const int C = s * 16 + (l & 15);
            bf[2 * s]     = *(const bf16x8*)(B + C * 64 + (g0 << 3));
            bf[2 * s + 1] = *(const bf16x8*)(B + C * 64 + (g1 << 3));
        }
        // write tile t+1 into Bt[cur^1] (its readers finished at t-1's barrier)
        if (t + 1 < 64) {
            #pragma unroll
            for (int j = 0; j < 4; ++j)
                *(bf16x8*)(&Bt[cur ^ 1][scol * 64 + (((jb + j) ^ (scol & 7)) << 3)]) = st[j];
        }
        // issue tile t+2's global loads (complete during next iteration's compute)
        if (t + 2 < 64) {
            const short* gs = gsrc0 + ((size_t)(t + 2) << 13);
            #pragma unroll
            for (int j = 0; j < 4; ++j) st[j] = *(const bf16x8*)(gs + j * 8);
        }
        // 8 independent {2 MFMA + maintenance} chains
        #pragma unroll
        for (int s = 0; s < 8; ++s) {
            f32x4 acc = {0.0f, 0.0f, 0.0f, 0.0f};
            acc = __builtin_amdgcn_mfma_f32_16x16x32_bf16(a0, bf[2 * s], acc, 0, 0, 0);
            acc = __builtin_amdgcn_mfma_f32_16x16x32_bf16(a1, bf[2 * s + 1], acc, 0, 0, 0);
            const unsigned invcol = (unsigned)(invbase - (t << 7) - (s << 4));
            #pragma unroll
            for (int r = 0; r < 4; ++r) {
                const unsigned key = ((__float_as_uint(acc[r]) ^ 0x80000000u) & 0xFFFFC000u) | invcol;
                ins6(keys[r], key);
            }
        }
        __syncthreads();   // reads of cur done AND write of cur^1 done
        cur ^= 1;
    }

    // lane's 4 acc rows are (l>>4)*4 + r within the wave's strip; 16 classes x 6 = 96/row/split
    #pragma unroll
    for (int r = 0; r < 4; ++r) {
        const int row = r0 + ((l >> 4) << 2) + r;
        int* cp = cand + ((size_t)(sp * N_NODES + row)) * 96 + (l & 15) * 6;
        #pragma unroll
        for (int t = 0; t < 6; ++t) cp[t] = 16383 - (int)(keys[r][t] & 0x3FFFu);
    }
}

// ---------------- refine2: 512-thread, 6-deep phase-split staging; writes out directly ----------------
__global__ __launch_bounds__(512) void refine2_kernel(
    const float* __restrict__ F, const int* __restrict__ cand,
    float* __restrict__ out)
{
    __shared__ float sfr[64];
    __shared__ float scand[192 * 65];   // 49920 B
    __shared__ float sval[192];
    __shared__ int   sidx[192];
    const int t = threadIdx.x;
    const int row = blockIdx.x;

    if (t < 64) sfr[t] = F[(size_t)row * 64 + t];

    // stage 192 candidate rows: 32 groups x 6 slots, 16 threads x float4 = 256B per row
    const int g = t >> 4, qq = t & 15;   // g in 0..31
    int cidx6[6];
    #pragma unroll
    for (int i = 0; i < 6; ++i) {
        const int s = i * 32 + g;
        const int sp = (s >= 96) ? 1 : 0;
        const int slot = s - 96 * sp;
        cidx6[i] = cand[((size_t)(sp * N_NODES + row)) * 96 + slot];
    }
    float4 v6[6];
    #pragma unroll
    for (int i = 0; i < 6; ++i)
        v6[i] = *(const float4*)(F + ((size_t)cidx6[i] << 6) + (qq << 2));
    #pragma unroll
    for (int i = 0; i < 6; ++i) {
        float* d = &scand[(i * 32 + g) * 65 + (qq << 2)];
        d[0] = v6[i].x; d[1] = v6[i].y; d[2] = v6[i].z; d[3] = v6[i].w;
    }
    __syncthreads();

    if (t < 192) {
        const int sp = (t >= 96) ? 1 : 0;
        const int slot = t - 96 * sp;
        const int c = cand[((size_t)(sp * N_NODES + row)) * 96 + slot];
        const float* fp = &scand[t * 65];
        float acc = 0.0f;
        #pragma unroll 8
        for (int k = 0; k < 64; ++k) acc = fmaf(sfr[k], fp[k], acc);  // k-ascending exact chain
        sval[t] = acc; sidx[t] = c;
    }
    __syncthreads();

    if (t < 64) {
        float v0 = sval[t], v1 = sval[t + 64], v2 = sval[t + 128];
        int   i0 = sidx[t], i1 = sidx[t + 64], i2 = sidx[t + 128];
        #pragma unroll 1
        for (int it = 0; it < 8; ++it) {
            float bv = v0; int bi = i0;
            if (v1 > bv || (v1 == bv && i1 < bi)) { bv = v1; bi = i1; }
            if (v2 > bv || (v2 == bv && i2 < bi)) { bv = v2; bi = i2; }
            #pragma unroll
            for (int off = 32; off > 0; off >>= 1) {
                float ov = __shfl_xor(bv, off);
                int   oi = __shfl_xor(bi, off);
                if (ov > bv || (ov == bv && oi < bi)) { bv = ov; bi = oi; }
            }
            if (t == 0) {
                out[(size_t)row * 8 + it]          = bv;          // topk_vals
                out[131072 + (size_t)row * 8 + it] = (float)row;  // new_edge_index row 0
                out[262144 + (size_t)row * 8 + it] = (float)bi;   // new_edge_index row 1
            }
            if (i0 == bi) v0 = -3.4e38f;   // cols distinct per row
            if (i1 == bi) v1 = -3.4e38f;
            if (i2 == bi) v2 = -3.4e38f;
        }
    }
}

__global__ void canary_kernel(float* out, float code) {
    out[0] = code;
}

// ---------------- launch ----------------
extern "C" void kernel_launch(void* const* d_in, const int* in_sizes, int n_in,
                              void* d_out, int out_size, void* d_ws, size_t ws_size,
                              hipStream_t stream)
{
    const float* x   = (const float*)d_in[0];
    const void*  ei  = d_in[1];
    const float* W1  = (const float*)d_in[2];  const float* b1  = (const float*)d_in[3];
    const float* W2  = (const float*)d_in[4];  const float* b2  = (const float*)d_in[5];
    const float* W3  = (const float*)d_in[6];  const float* b3  = (const float*)d_in[7];
    const float* W4  = (const float*)d_in[8];  const float* b4  = (const float*)d_in[9];
    const float* Wg1 = (const float*)d_in[10]; const float* bg1 = (const float*)d_in[11];
    const float* Wg2 = (const float*)d_in[12]; const float* bg2 = (const float*)d_in[13];
    float* out = (float*)d_out;

    // workspace layout (stream-ordered overlays):
    //   g32   [0, 4M)
    //   F32   [4M, 8M)
    //   Fb    [8M, 10M)
    //   cand  [10M, 22M)  -- first 1.1M overlaid by CSR scratch (dead before screen):
    //       ecol_s [10M, 11M), offs [11M, +68K)
    //   deg [23M, +64K) cursor [23M+64K, +128K) (single memset) dinv [23M+128K, +192K)
    char* ws = (char*)d_ws;
    float* g32 = (float*)(ws);
    float* F32 = (float*)(ws + ((size_t)4 << 20));
    short* Fb  = (short*)(ws + ((size_t)8 << 20));
    int*   cand   = (int*)(ws + ((size_t)10 << 20));
    int*   ecol_s = (int*)(ws + ((size_t)10 << 20));
    int*   offs   = (int*)(ws + ((size_t)11 << 20));
    int*   deg    = (int*)(ws + ((size_t)23 << 20));
    int*   cursor = (int*)(ws + ((size_t)23 << 20) + (1u << 16));
    float* dinvf  = (float*)(ws + ((size_t)23 << 20) + (2u << 16));

    const size_t NEEDED = ((size_t)23 << 20) + (3u << 16);
    if (ws_size < NEEDED || n_in < 14) {
        canary_kernel<<<1, 1, 0, stream>>>(out, ws_size < NEEDED ? 5000.0f : 3000.0f);
        return;
    }

    hipMemsetAsync(deg, 0, 2 * N_NODES * sizeof(int), stream);   // deg + cursor (adjacent)

    deg_kernel<<<E_EDGES / 256, 256, 0, stream>>>(ei, deg);
    scan_kernel<<<1, 256, 0, stream>>>(deg, offs, dinvf);
    scatter_kernel<<<E_EDGES / 256, 256, 0, stream>>>(ei, offs, cursor, ecol_s);
    mlp_kernel<<<N_NODES / 16, 256, 0, stream>>>(x, W1, b1, W2, b2, W3, b3, W4, b4, Wg1, bg1, Wg2, bg2, g32);
    aggcsr_kernel<<<N_NODES / 4, 256, 0, stream>>>(offs, ecol_s, dinvf, g32, F32, Fb);
    screen_kernel<<<512, 256, 0, stream>>>(Fb, cand);
    refine2_kernel<<<N_NODES, 512, 0, stream>>>(F32, cand, out);
}

// Round 19
// 465.045 us; speedup vs baseline: 1.3729x; 1.0225x over previous
//
#include <hip/hip_runtime.h>
#include <hip/hip_bf16.h>

#define N_NODES 16384
#define E_EDGES 262144
#define IN_DIM 512

// fixed-point scale for deterministic aggregation
#define AGG_SCALE 1099511627776.0   // 2^40
#define AGG_INV   (1.0/1099511627776.0)

typedef __attribute__((ext_vector_type(8))) short bf16x8;
typedef __attribute__((ext_vector_type(4))) float f32x4;

// ---------------- inline edge dtype detection (per-wave uniform) ----------------
__device__ __forceinline__ int detect64(const void* __restrict__ ei) {
    const unsigned long long v = ((const unsigned long long*)ei)[threadIdx.x & 63];
    return __all(v < 16384ull) ? 1 : 0;
}

__device__ __forceinline__ int edge_at(const void* __restrict__ ei, int is64, int pos) {
    return is64 ? (int)(((const long long*)ei)[pos]) : ((const int*)ei)[pos];
}

// ---------------- degree ----------------
__global__ __launch_bounds__(256) void deg_kernel(const void* __restrict__ ei,
                                                  int* __restrict__ deg) {
    const int is64 = detect64(ei);
    int e = blockIdx.x * 256 + threadIdx.x;
    int r = edge_at(ei, is64, e);
    if (r >= 0 && r < N_NODES) atomicAdd(&deg[r], 1);
}

// ---------------- exclusive prefix scan of deg -> offs; also dinv (fused) ----------------
__global__ __launch_bounds__(256) void scan_kernel(const int* __restrict__ deg, int* __restrict__ offs,
                                                   float* __restrict__ dinv) {
    __shared__ int part[257];
    const int t = threadIdx.x;
    const int base = t * 64;
    int s = 0;
    #pragma unroll 4
    for (int i = 0; i < 64; ++i) s += deg[base + i];
    part[t + 1] = s;
    if (t == 0) part[0] = 0;
    __syncthreads();
    if (t == 0) {
        int acc = 0;
        for (int i = 1; i <= 256; ++i) { acc += part[i]; part[i] = acc; }
    }
    __syncthreads();
    int run = part[t];                      // exclusive offset of chunk t
    for (int i = 0; i < 64; ++i) {
        const int d = deg[base + i];
        offs[base + i] = run; run += d;
        dinv[base + i] = (d > 0) ? __fdiv_rn(1.0f, __fsqrt_rn((float)d)) : 0.0f;
    }
    if (t == 255) offs[N_NODES] = run;
}

// ---------------- scatter edges into CSR slots ----------------
__global__ __launch_bounds__(256) void scatter_kernel(
    const void* __restrict__ ei,
    const int* __restrict__ offs, int* __restrict__ cursor, int* __restrict__ ecol_s)
{
    const int is64 = detect64(ei);
    int e = blockIdx.x * 256 + threadIdx.x;
    int r  = edge_at(ei, is64, e);
    if (r < 0 || r >= N_NODES) return;
    int cc = edge_at(ei, is64, E_EDGES + e);
    int pos = atomicAdd(&cursor[r], 1);
    ecol_s[offs[r] + pos] = (cc >= 0 && cc < N_NODES) ? cc : -1;
}

// ---------------- MLP: f32, k-ascending single-accumulator fmaf chains ----------------
// float4 loads (4x fewer issue slots); per-accumulator k-ascending order preserved exactly.
__device__ __forceinline__ void dense_layer32(float (*hsw)[64], int c,
                                              const float* __restrict__ WP,
                                              const float* __restrict__ BP,
                                              bool relu, bool last,
                                              float* __restrict__ gout, int n0)
{
    float s0 = 0.0f, s1 = 0.0f, s2 = 0.0f, s3 = 0.0f;
    #pragma unroll 4
    for (int k = 0; k < 64; k += 4) {
        const float4 h0 = *(const float4*)&hsw[0][k];
        const float4 h1 = *(const float4*)&hsw[1][k];
        const float4 h2 = *(const float4*)&hsw[2][k];
        const float4 h3 = *(const float4*)&hsw[3][k];
        const float w0 = WP[k * 64 + c];
        const float w1 = WP[(k + 1) * 64 + c];
        const float w2 = WP[(k + 2) * 64 + c];
        const float w3 = WP[(k + 3) * 64 + c];
        s0 = fmaf(h0.x, w0, s0); s0 = fmaf(h0.y, w1, s0); s0 = fmaf(h0.z, w2, s0); s0 = fmaf(h0.w, w3, s0);
        s1 = fmaf(h1.x, w0, s1); s1 = fmaf(h1.y, w1, s1); s1 = fmaf(h1.z, w2, s1); s1 = fmaf(h1.w, w3, s1);
        s2 = fmaf(h2.x, w0, s2); s2 = fmaf(h2.y, w1, s2); s2 = fmaf(h2.z, w2, s2); s2 = fmaf(h2.w, w3, s2);
        s3 = fmaf(h3.x, w0, s3); s3 = fmaf(h3.y, w1, s3); s3 = fmaf(h3.z, w2, s3); s3 = fmaf(h3.w, w3, s3);
    }
    const float bv = BP[c];
    s0 += bv; s1 += bv; s2 += bv; s3 += bv;
    if (relu) { s0 = fmaxf(s0, 0.0f); s1 = fmaxf(s1, 0.0f); s2 = fmaxf(s2, 0.0f); s3 = fmaxf(s3, 0.0f); }
    __syncthreads();
    if (last) {
        gout[(size_t)(n0 + 0) * 64 + c] = s0;
        gout[(size_t)(n0 + 1) * 64 + c] = s1;
        gout[(size_t)(n0 + 2) * 64 + c] = s2;
        gout[(size_t)(n0 + 3) * 64 + c] = s3;
    } else {
        hsw[0][c] = s0; hsw[1][c] = s1; hsw[2][c] = s2; hsw[3][c] = s3;
    }
    __syncthreads();
}

__global__ __launch_bounds__(256) void mlp_kernel(
    const float* __restrict__ x,
    const float* __restrict__ W1, const float* __restrict__ b1,
    const float* __restrict__ W2, const float* __restrict__ b2,
    const float* __restrict__ W3, const float* __restrict__ b3,
    const float* __restrict__ W4, const float* __restrict__ b4,
    const float* __restrict__ Wg1, const float* __restrict__ bg1,
    const float* __restrict__ Wg2, const float* __restrict__ bg2,
    float* __restrict__ g32)
{
    __shared__ float hs[4][4][64];
    const int w = threadIdx.x >> 6;
    const int c = threadIdx.x & 63;
    const int n0 = blockIdx.x * 16 + w * 4;

    float a0 = 0.0f, a1 = 0.0f, a2 = 0.0f, a3 = 0.0f;
    const float* xp = x + (size_t)n0 * IN_DIM;
    #pragma unroll 2
    for (int k = 0; k < IN_DIM; k += 4) {
        const float4 x0 = *(const float4*)(xp + k);
        const float4 x1 = *(const float4*)(xp + IN_DIM + k);
        const float4 x2 = *(const float4*)(xp + 2 * IN_DIM + k);
        const float4 x3 = *(const float4*)(xp + 3 * IN_DIM + k);
        const float w0 = W1[k * 64 + c];
        const float w1 = W1[(k + 1) * 64 + c];
        const float w2 = W1[(k + 2) * 64 + c];
        const float w3 = W1[(k + 3) * 64 + c];
        a0 = fmaf(x0.x, w0, a0); a0 = fmaf(x0.y, w1, a0); a0 = fmaf(x0.z, w2, a0); a0 = fmaf(x0.w, w3, a0);
        a1 = fmaf(x1.x, w0, a1); a1 = fmaf(x1.y, w1, a1); a1 = fmaf(x1.z, w2, a1); a1 = fmaf(x1.w, w3, a1);
        a2 = fmaf(x2.x, w0, a2); a2 = fmaf(x2.y, w1, a2); a2 = fmaf(x2.z, w2, a2); a2 = fmaf(x2.w, w3, a2);
        a3 = fmaf(x3.x, w0, a3); a3 = fmaf(x3.y, w1, a3); a3 = fmaf(x3.z, w2, a3); a3 = fmaf(x3.w, w3, a3);
    }
    const float bv = b1[c];
    hs[w][0][c] = fmaxf(a0 + bv, 0.0f);
    hs[w][1][c] = fmaxf(a1 + bv, 0.0f);
    hs[w][2][c] = fmaxf(a2 + bv, 0.0f);
    hs[w][3][c] = fmaxf(a3 + bv, 0.0f);
    __syncthreads();

    dense_layer32(hs[w], c, W2, b2, false, false, g32, n0);
    dense_layer32(hs[w], c, W3, b3, true,  false, g32, n0);
    dense_layer32(hs[w], c, W4, b4, false, false, g32, n0);
    dense_layer32(hs[w], c, Wg1, bg1, true, false, g32, n0);
    dense_layer32(hs[w], c, Wg2, bg2, false, true, g32, n0);
}

// ---------------- CSR aggregation + finalize (fused): one wave per row ----------------
__global__ __launch_bounds__(256) void aggcsr_kernel(
    const int* __restrict__ offs, const int* __restrict__ ecol_s,
    const float* __restrict__ dinv, const float* __restrict__ g32,
    float* __restrict__ F32, short* __restrict__ Fb)
{
    const int r = (blockIdx.x << 2) + (threadIdx.x >> 6);
    const int h = threadIdx.x & 63;
    const float dr = dinv[r];
    const int b = offs[r], e2 = offs[r + 1];
    long long sum = 0;
    #pragma unroll 8
    for (int i = b; i < e2; ++i) {
        const int cc = ecol_s[i];
        if (cc < 0) continue;
        const float m = __fmul_rn(__fmul_rn(dr, dinv[cc]), g32[((size_t)cc << 6) + h]);
        sum += __double2ll_rn((double)m * AGG_SCALE);
    }
    const float a = (float)((double)sum * AGG_INV);
    const int idx = (r << 6) + h;
    const float f = g32[idx] - a;
    F32[idx] = f;
    __hip_bfloat16 hb = __float2bfloat16(f);
    Fb[idx] = *(short*)&hb;
}

// ---------------- MFMA bf16 screening: LDS-staged B panel, single-barrier pipeline ----------------
// Key: (bits & 0xFFFFC000) ^ (0x80000000 | invcol)  — identical to the prior
// ((bits^0x80000000)&mask)|invcol (low bits disjoint), but 2 VALU ops.
__device__ __forceinline__ void ins6(unsigned* k, unsigned x) {
    const unsigned r0 = max(k[0], x);
    k[5] = min(k[4], max(k[5], x));
    k[4] = min(k[3], max(k[4], x));
    k[3] = min(k[2], max(k[3], x));
    k[2] = min(k[1], max(k[2], x));
    k[1] = min(k[0], max(k[1], x));
    k[0] = r0;
}

__global__ __launch_bounds__(256) void screen_kernel(
    const short* __restrict__ Fb, int* __restrict__ cand)
{
    __shared__ short Bt[2][128 * 64];   // 2 x 16 KB: [buf][col*64 + swizzled k]
    const int l = threadIdx.x & 63;
    const int w = threadIdx.x >> 6;
    const int rb = blockIdx.x >> 1;
    const int sp = blockIdx.x & 1;
    const int r0 = rb * 64 + w * 16;
    const int c0 = sp * 8192;

    // A fragments: lane l <- Fb[r0 + (l&15)][8*(l>>4) .. +7] and +32
    const short* ap = Fb + ((size_t)(r0 + (l & 15)) << 6) + ((l >> 4) << 3);
    const bf16x8 a0 = *(const bf16x8*)(ap);
    const bf16x8 a1 = *(const bf16x8*)(ap + 32);

    unsigned keys[4][6];
    #pragma unroll
    for (int r = 0; r < 4; ++r)
        #pragma unroll
        for (int t = 0; t < 6; ++t) keys[r][t] = 0u;

    // staging role: col = tid&127, granules jb..jb+3 (64B of the 128B row)
    const int scol = threadIdx.x & 127;
    const int jb = (threadIdx.x >> 7) * 4;
    const short* gsrc0 = Fb + ((size_t)(c0 + scol) << 6) + jb * 8;

    // prologue: stage tile 0; preload tile 1 into st
    bf16x8 st[4];
    #pragma unroll
    for (int j = 0; j < 4; ++j) st[j] = *(const bf16x8*)(gsrc0 + j * 8);
    #pragma unroll
    for (int j = 0; j < 4; ++j)
        *(bf16x8*)(&Bt[0][scol * 64 + (((jb + j) ^ (scol & 7)) << 3)]) = st[j];
    #pragma unroll
    for (int j = 0; j < 4; ++j) st[j] = *(const bf16x8*)(gsrc0 + (1 << 13) + j * 8);
    __syncthreads();

    const unsigned invb = 0x80000000u | (unsigned)(16383 - c0 - (l & 15));
    const int g0 = (l >> 4) ^ (l & 7);
    const int g1 = ((l >> 4) + 4) ^ (l & 7);
    int cur = 0;

    #pragma unroll 1
    for (int t = 0; t < 64; ++t) {
        // hoist ALL b-fragment LDS reads for tile t (16 independent ds_read_b128)
        const short* B = &Bt[cur][0];
        bf16x8 bf[16];
        #pragma unroll
        for (int s = 0; s < 8; ++s) {
            const int C = s * 16 + (l & 15);
            bf[2 * s]     = *(const bf16x8*)(B + C * 64 + (g0 << 3));
            bf[2 * s + 1] = *(const bf16x8*)(B + C * 64 + (g1 << 3));
        }
        // write tile t+1 into Bt[cur^1] (its readers finished at t-1's barrier)
        if (t + 1 < 64) {
            #pragma unroll
            for (int j = 0; j < 4; ++j)
                *(bf16x8*)(&Bt[cur ^ 1][scol * 64 + (((jb + j) ^ (scol & 7)) << 3)]) = st[j];
        }
        // issue tile t+2's global loads (complete during next iteration's compute)
        if (t + 2 < 64) {
            const short* gs = gsrc0 + ((size_t)(t + 2) << 13);
            #pragma unroll
            for (int j = 0; j < 4; ++j) st[j] = *(const bf16x8*)(gs + j * 8);
        }
        // 8 independent {2 MFMA + maintenance} chains
        #pragma unroll
        for (int s = 0; s < 8; ++s) {
            f32x4 acc = {0.0f, 0.0f, 0.0f, 0.0f};
            acc = __builtin_amdgcn_mfma_f32_16x16x32_bf16(a0, bf[2 * s], acc, 0, 0, 0);
            acc = __builtin_amdgcn_mfma_f32_16x16x32_bf16(a1, bf[2 * s + 1], acc, 0, 0, 0);
            const unsigned xv = invb - (unsigned)((t << 7) + (s << 4));
            #pragma unroll
            for (int r = 0; r < 4; ++r) {
                const unsigned key = (__float_as_uint(acc[r]) & 0xFFFFC000u) ^ xv;
                ins6(keys[r], key);
            }
        }
        __syncthreads();   // reads of cur done AND write of cur^1 done
        cur ^= 1;
    }

    // lane's 4 acc rows are (l>>4)*4 + r within the wave's strip; 16 classes x 6 = 96/row/split
    #pragma unroll
    for (int r = 0; r < 4; ++r) {
        const int row = r0 + ((l >> 4) << 2) + r;
        int* cp = cand + ((size_t)(sp * N_NODES + row)) * 96 + (l & 15) * 6;
        #pragma unroll
        for (int t = 0; t < 6; ++t) cp[t] = 16383 - (int)(keys[r][t] & 0x3FFFu);
    }
}

// ---------------- refine2: b128-LDS phase-split staging; F[row] from global regs ----------------
__global__ __launch_bounds__(512) void refine2_kernel(
    const float* __restrict__ F, const int* __restrict__ cand,
    float* __restrict__ out)
{
    __shared__ float scand[192 * 68];   // 52224 B, 16B-aligned rows (stride 68)
    __shared__ float sval[192];
    __shared__ int   sidx[192];
    const int t = threadIdx.x;
    const int row = blockIdx.x;

    // stage 192 candidate rows: 32 groups x 6 slots, 16 threads x float4 = 256B per row
    const int g = t >> 4, qq = t & 15;   // g in 0..31
    int cidx6[6];
    #pragma unroll
    for (int i = 0; i < 6; ++i) {
        const int s = i * 32 + g;
        const int sp = (s >= 96) ? 1 : 0;
        const int slot = s - 96 * sp;
        cidx6[i] = cand[((size_t)(sp * N_NODES + row)) * 96 + slot];
    }
    float4 v6[6];
    #pragma unroll
    for (int i = 0; i < 6; ++i)
        v6[i] = *(const float4*)(F + ((size_t)cidx6[i] << 6) + (qq << 2));
    #pragma unroll
    for (int i = 0; i < 6; ++i)
        *(float4*)(&scand[(i * 32 + g) * 68 + (qq << 2)]) = v6[i];
    __syncthreads();

    if (t < 192) {
        const int sp = (t >= 96) ? 1 : 0;
        const int slot = t - 96 * sp;
        const int c = cand[((size_t)(sp * N_NODES + row)) * 96 + slot];
        const float* fp = &scand[t * 68];
        const float* frp = F + ((size_t)row << 6);
        float acc = 0.0f;
        #pragma unroll 4
        for (int j = 0; j < 16; ++j) {
            const float4 a = *(const float4*)(frp + 4 * j);   // L1-broadcast global
            const float4 b = *(const float4*)(fp + 4 * j);    // ds_read_b128
            acc = fmaf(a.x, b.x, acc);
            acc = fmaf(a.y, b.y, acc);
            acc = fmaf(a.z, b.z, acc);
            acc = fmaf(a.w, b.w, acc);
        }
        sval[t] = acc; sidx[t] = c;
    }
    __syncthreads();

    if (t < 64) {
        float v0 = sval[t], v1 = sval[t + 64], v2 = sval[t + 128];
        int   i0 = sidx[t], i1 = sidx[t + 64], i2 = sidx[t + 128];
        #pragma unroll 1
        for (int it = 0; it < 8; ++it) {
            float bv = v0; int bi = i0;
            if (v1 > bv || (v1 == bv && i1 < bi)) { bv = v1; bi = i1; }
            if (v2 > bv || (v2 == bv && i2 < bi)) { bv = v2; bi = i2; }
            #pragma unroll
            for (int off = 32; off > 0; off >>= 1) {
                float ov = __shfl_xor(bv, off);
                int   oi = __shfl_xor(bi, off);
                if (ov > bv || (ov == bv && oi < bi)) { bv = ov; bi = oi; }
            }
            if (t == 0) {
                out[(size_t)row * 8 + it]          = bv;          // topk_vals
                out[131072 + (size_t)row * 8 + it] = (float)row;  // new_edge_index row 0
                out[262144 + (size_t)row * 8 + it] = (float)bi;   // new_edge_index row 1
            }
            if (i0 == bi) v0 = -3.4e38f;   // cols distinct per row
            if (i1 == bi) v1 = -3.4e38f;
            if (i2 == bi) v2 = -3.4e38f;
        }
    }
}

__global__ void canary_kernel(float* out, float code) {
    out[0] = code;
}

// ---------------- launch ----------------
extern "C" void kernel_launch(void* const* d_in, const int* in_sizes, int n_in,
                              void* d_out, int out_size, void* d_ws, size_t ws_size,
                              hipStream_t stream)
{
    const float* x   = (const float*)d_in[0];
    const void*  ei  = d_in[1];
    const float* W1  = (const float*)d_in[2];  const float* b1  = (const float*)d_in[3];
    const float* W2  = (const float*)d_in[4];  const float* b2  = (const float*)d_in[5];
    const float* W3  = (const float*)d_in[6];  const float* b3  = (const float*)d_in[7];
    const float* W4  = (const float*)d_in[8];  const float* b4  = (const float*)d_in[9];
    const float* Wg1 = (const float*)d_in[10]; const float* bg1 = (const float*)d_in[11];
    const float* Wg2 = (const float*)d_in[12]; const float* bg2 = (const float*)d_in[13];
    float* out = (float*)d_out;

    // workspace layout (stream-ordered overlays):
    //   g32   [0, 4M)
    //   F32   [4M, 8M)
    //   Fb    [8M, 10M)
    //   cand  [10M, 22M)  -- first 1.1M overlaid by CSR scratch (dead before screen):
    //       ecol_s [10M, 11M), offs [11M, +68K)
    //   deg [23M, +64K) cursor [23M+64K, +128K) (single memset) dinv [23M+128K, +192K)
    char* ws = (char*)d_ws;
    float* g32 = (float*)(ws);
    float* F32 = (float*)(ws + ((size_t)4 << 20));
    short* Fb  = (short*)(ws + ((size_t)8 << 20));
    int*   cand   = (int*)(ws + ((size_t)10 << 20));
    int*   ecol_s = (int*)(ws + ((size_t)10 << 20));
    int*   offs   = (int*)(ws + ((size_t)11 << 20));
    int*   deg    = (int*)(ws + ((size_t)23 << 20));
    int*   cursor = (int*)(ws + ((size_t)23 << 20) + (1u << 16));
    float* dinvf  = (float*)(ws + ((size_t)23 << 20) + (2u << 16));

    const size_t NEEDED = ((size_t)23 << 20) + (3u << 16);
    if (ws_size < NEEDED || n_in < 14) {
        canary_kernel<<<1, 1, 0, stream>>>(out, ws_size < NEEDED ? 5000.0f : 3000.0f);
        return;
    }

    hipMemsetAsync(deg, 0, 2 * N_NODES * sizeof(int), stream);   // deg + cursor (adjacent)

    deg_kernel<<<E_EDGES / 256, 256, 0, stream>>>(ei, deg);
    scan_kernel<<<1, 256, 0, stream>>>(deg, offs, dinvf);
    scatter_kernel<<<E_EDGES / 256, 256, 0, stream>>>(ei, offs, cursor, ecol_s);
    mlp_kernel<<<N_NODES / 16, 256, 0, stream>>>(x, W1, b1, W2, b2, W3, b3, W4, b4, Wg1, bg1, Wg2, bg2, g32);
    aggcsr_kernel<<<N_NODES / 4, 256, 0, stream>>>(offs, ecol_s, dinvf, g32, F32, Fb);
    screen_kernel<<<512, 256, 0, stream>>>(Fb, cand);
    refine2_kernel<<<N_NODES, 512, 0, stream>>>(F32, cand, out);
}